// Round 1
// baseline (354.426 us; speedup 1.0000x reference)
//
#include <hip/hip_runtime.h>

typedef _Float16 f16x8 __attribute__((ext_vector_type(8)));
typedef _Float16 f16x4 __attribute__((ext_vector_type(4)));
typedef float f32x4 __attribute__((ext_vector_type(4)));

// Async global->LDS, 16B per lane. LDS dest must be wave-uniform base; HW adds lane*16.
__device__ __forceinline__ void lds_load16(const _Float16* g, _Float16* l) {
    __builtin_amdgcn_global_load_lds(
        (const __attribute__((address_space(1))) void*)g,
        (__attribute__((address_space(3))) void*)l,
        16, 0, 0);
}

// ---------------------------------------------------------------------------
// NT GEMM core: C[M,N] = A[M,K]*B[N,K]^T. f16 in, fp32 acc.
// Tile 256x128, BK=32, 256 thr = 4 waves in 2x2, wave-tile 128x64 (acc[8][4]).
// LDS intensity 42.7 FLOP/byte (was 16 at 64x64 wave-tile) -> LDS pipe no
// longer the ceiling. 48 KB double-buffered LDS, 1 barrier/K-iter, all-async
// global_load_lds staging, XCD pin on bx.
//
// Bank-conflict fix (was exactly 4 extra cyc per ds_read_b128): 16B-chunk
// XOR swizzle  chunk' = chunk ^ ((row>>1)&3).  global_load_lds writes
// linearly, so the swizzle is applied on the per-lane GLOBAL source address
// (LDS[r][c] holds global chunk c^sw(r)) and inverted on the ds_read side
// (read chunk kq at c = kq^sw(r)). sw(r) for read rows reduces to (ln>>1)&3.
//
// MODE 0: triple projection, z in {0,1,2}:
//   z=0: q  = Xqh@WqT^T + bq[n]   z=1: k = Xkh@WkT^T + bk[n]   (ldc=1024)
//   z=2: vT = WvT@Xvh^T + bv[m]   (ldc=8192)
// MODE 3: S~ = exp((q k^T)/32) f16 + atomic f32 row sums; z = batch
// MODE 5: out = (S~ @ v) * (1/rowsum[row]) f32 store; z = batch
// ---------------------------------------------------------------------------
template <int MODE>
__global__ __launch_bounds__(256, 2)
void gemm_core(const _Float16* A0, const _Float16* B0, void* C0, const float* b0,
               const _Float16* A1, const _Float16* B1, void* C1, const float* b1,
               const _Float16* A2, const _Float16* B2, void* C2, const float* b2,
               float* rowsum)
{
    constexpr int K   = (MODE == 5) ? 2048 : 1024;
    constexpr int LDA = (MODE == 5) ? 2048 : 1024;
    constexpr int LDB = (MODE == 5) ? 8192 : 1024;

    const int z = blockIdx.z;
    const int bx = blockIdx.x, by = blockIdx.y;

    __shared__ __align__(16) _Float16 As[2][256 * 32];
    __shared__ __align__(16) _Float16 Bs[2][128 * 32];

    const int t    = threadIdx.x;
    const int w    = t >> 6;
    const int lane = t & 63;
    const int ln   = lane & 15;
    const int kq   = lane >> 4;
    const int wm   = (w & 1) * 128;       // wave row offset (2 waves over 256)
    const int wn   = (w >> 1) * 64;       // wave col offset (2 waves over 128)

    const _Float16* A;
    const _Float16* B;
    size_t cbase = 0;
    int m0, n0;

    if (MODE == 0) {
        // grid (8,32,3); XCD = bx.
        A = z == 0 ? A0 : z == 1 ? A1 : A2;
        B = z == 0 ? B0 : z == 1 ? B1 : B2;
        if (z == 2) { m0 = (by & 3) * 256; n0 = ((by >> 2) * 8 + bx) * 128; }
        else        { m0 = by * 256;       n0 = bx * 128; }
    } else if (MODE == 3) {
        // grid (8,16,4); XCD = bx (k-panel tn in {bx, bx+8} L2-resident).
        A = A0 + (size_t)z * 2048 * 1024;      // q slice
        B = B0 + (size_t)z * 2048 * 1024;      // k slice
        cbase = (size_t)z * 2048 * 2048;
        rowsum += z * 2048;
        m0 = (by >> 1) * 256;
        n0 = ((by & 1) * 8 + bx) * 128;
    } else {
        // grid (8,8,4); XCD = bx (vT 128x2048 panel L2-resident).
        A = A0 + (size_t)z * 2048 * 2048;      // S~ slice
        B = B0 + (size_t)z * 2048;             // vT col offset
        cbase = (size_t)z * 2048 * 1024;
        rowsum += z * 2048;
        m0 = by * 256;
        n0 = bx * 128;
    }

    // Staging: thread t covers row r4=t>>2 (+64s), 16B chunk (t&3). Source is
    // pre-swizzled so LDS[r][c] = global[r][c ^ ((r>>1)&3)] with linear dest.
    const int r4 = t >> 2;
    const int sc = ((t & 3) ^ ((t >> 3) & 3)) * 8;      // swizzled src chunk
    const _Float16* gA = A + (size_t)(m0 + r4) * LDA + sc;
    const _Float16* gB = B + (size_t)(n0 + r4) * LDB + sc;

    auto stage = [&](int b, int k0) {
#pragma unroll
        for (int s = 0; s < 4; ++s)
            lds_load16(gA + k0 + (size_t)s * 64 * LDA, As[b] + s * 2048 + w * 512);
        lds_load16(gB + k0,                     Bs[b] + w * 512);
        lds_load16(gB + k0 + (size_t)64 * LDB,  Bs[b] + 2048 + w * 512);
    };

    // Read side: global chunk kq of row R lives at chunk kq ^ ((R>>1)&3);
    // wm, wn, i*16 are 0 mod 8 so sw(R) = (ln>>1)&3 (per-thread constant).
    const int swz   = (kq ^ ((ln >> 1) & 3)) * 8;
    const int abase = (wm + ln) * 32 + swz;
    const int bbase = (wn + ln) * 32 + swz;

    f32x4 acc[8][4] = {};

    stage(0, 0);
    int cur = 0;
#pragma unroll 2
    for (int k0 = 0; k0 < K; k0 += 32) {
        __syncthreads();               // drains cur-buf loads (issued 1 phase ago)
        if (k0 + 32 < K) stage(cur ^ 1, k0 + 32);
        const _Float16* Ab = As[cur] + abase;
        const _Float16* Bb = Bs[cur] + bbase;
        f16x8 af[8], bf[4];
#pragma unroll
        for (int i = 0; i < 8; ++i)
            af[i] = *(const f16x8*)(Ab + i * 512);
#pragma unroll
        for (int j = 0; j < 4; ++j)
            bf[j] = *(const f16x8*)(Bb + j * 512);
#pragma unroll
        for (int i = 0; i < 8; ++i)
#pragma unroll
            for (int j = 0; j < 4; ++j)
                acc[i][j] = __builtin_amdgcn_mfma_f32_16x16x32_f16(af[i], bf[j], acc[i][j], 0, 0, 0);
        cur ^= 1;
    }

    // Epilogue. C/D layout: col = lane&15, row = (lane>>4)*4 + reg.
    if (MODE == 0) {
        _Float16* Cp = (_Float16*)(z == 0 ? C0 : z == 1 ? C1 : C2);
        const float* bp = z == 0 ? b0 : z == 1 ? b1 : b2;
        const int ldc = (z == 2) ? 8192 : 1024;
#pragma unroll
        for (int i = 0; i < 8; ++i) {
            const int rbase = m0 + wm + i * 16 + kq * 4;
#pragma unroll
            for (int j = 0; j < 4; ++j) {
                const int gcol = n0 + wn + j * 16 + ln;
#pragma unroll
                for (int r = 0; r < 4; ++r) {
                    float vv = acc[i][j][r] + (z == 2 ? bp[rbase + r] : bp[gcol]);
                    Cp[(size_t)(rbase + r) * ldc + gcol] = (_Float16)vv;
                }
            }
        }
    } else if (MODE == 3) {
        _Float16* Ch = (_Float16*)C0;
#pragma unroll
        for (int i = 0; i < 8; ++i) {
            const int rbase = m0 + wm + i * 16 + kq * 4;
            float rs[4] = {0.f, 0.f, 0.f, 0.f};
#pragma unroll
            for (int j = 0; j < 4; ++j) {
                const int gcol = n0 + wn + j * 16 + ln;
#pragma unroll
                for (int r = 0; r < 4; ++r) {
                    float e = __expf(acc[i][j][r] * 0.03125f);
                    Ch[cbase + (size_t)(rbase + r) * 2048 + gcol] = (_Float16)e;
                    rs[r] += e;
                }
            }
#pragma unroll
            for (int r = 0; r < 4; ++r) {
                float s = rs[r];
                s += __shfl_xor(s, 1);
                s += __shfl_xor(s, 2);
                s += __shfl_xor(s, 4);
                s += __shfl_xor(s, 8);
                if (ln == 0) atomicAdd(&rowsum[rbase + r], s);
            }
        }
    } else {
        float* Cf = (float*)C0;
#pragma unroll
        for (int i = 0; i < 8; ++i) {
            const int rbase = m0 + wm + i * 16 + kq * 4;
            float inv[4];
#pragma unroll
            for (int r = 0; r < 4; ++r) inv[r] = 1.f / rowsum[rbase + r];
#pragma unroll
            for (int j = 0; j < 4; ++j) {
                const int gcol = n0 + wn + j * 16 + ln;
#pragma unroll
                for (int r = 0; r < 4; ++r)
                    Cf[cbase + (size_t)(rbase + r) * 1024 + gcol] = acc[i][j][r] * inv[r];
            }
        }
    }
}

// ---------------------------------------------------------------------------
// Prep kernel, ONE launch. grid (8192, 4), 256 threads:
//   y in {0,1,2}: f32->f16 convert of X_y (float4/thread); y==0,x<32 zeros rowsum.
//   y==3, x<3072: 32x32 transpose tile of W_{x/1024} -> f16 W^T.
// ---------------------------------------------------------------------------
__global__ __launch_bounds__(256)
void prep(const float4* __restrict__ x0, _Float16* __restrict__ y0,
          const float4* __restrict__ x1, _Float16* __restrict__ y1,
          const float4* __restrict__ x2, _Float16* __restrict__ y2,
          const float* __restrict__ W0, _Float16* __restrict__ T0,
          const float* __restrict__ W1, _Float16* __restrict__ T1,
          const float* __restrict__ W2, _Float16* __restrict__ T2,
          float* __restrict__ rowsum)
{
    if (blockIdx.y < 3) {
        const size_t i = (size_t)blockIdx.x * 256 + threadIdx.x;
        const float4* x = blockIdx.y == 0 ? x0 : blockIdx.y == 1 ? x1 : x2;
        _Float16*    yy = blockIdx.y == 0 ? y0 : blockIdx.y == 1 ? y1 : y2;
        float4 f = x[i];
        f16x4 o = { (_Float16)f.x, (_Float16)f.y, (_Float16)f.z, (_Float16)f.w };
        *(f16x4*)(yy + i * 4) = o;
        if (blockIdx.y == 0 && blockIdx.x < 32)
            rowsum[blockIdx.x * 256 + threadIdx.x] = 0.f;
        return;
    }
    if (blockIdx.x >= 3072) return;
    const int zz = blockIdx.x >> 10;          // which W
    const int tb = blockIdx.x & 1023;         // tile id: 32x32 grid of 32x32 tiles
    const float* W = zz == 0 ? W0 : zz == 1 ? W1 : W2;
    _Float16*   WT = zz == 0 ? T0 : zz == 1 ? T1 : T2;
    __shared__ float tile[32][33];
    const int bxs = (tb & 31) * 32;           // source col block
    const int bys = (tb >> 5) * 32;           // source row block
    const int tx = threadIdx.x & 31;
    const int ty = threadIdx.x >> 5;          // 0..7
#pragma unroll
    for (int i = ty; i < 32; i += 8)
        tile[i][tx] = W[(size_t)(bys + i) * 1024 + bxs + tx];
    __syncthreads();
#pragma unroll
    for (int i = ty; i < 32; i += 8)
        WT[(size_t)(bxs + i) * 1024 + bys + tx] = (_Float16)tile[tx][i];
}

// ---------------------------------------------------------------------------
// B=4, Lq=Lk=2048, D=1024.
// prep (cvt+transpose+zero) -> {q,k,vT} one dispatch -> S~=exp(qk^T/32)+rowsum
// -> out = S~@v / rowsum.
// ---------------------------------------------------------------------------
extern "C" void kernel_launch(void* const* d_in, const int* in_sizes, int n_in,
                              void* d_out, int out_size, void* d_ws, size_t ws_size,
                              hipStream_t stream)
{
    const float* Xq = (const float*)d_in[0];
    const float* Xk = (const float*)d_in[1];
    const float* Xv = (const float*)d_in[2];
    const float* Wq = (const float*)d_in[3];
    const float* bq = (const float*)d_in[4];
    const float* Wk = (const float*)d_in[5];
    const float* bk = (const float*)d_in[6];
    const float* Wv = (const float*)d_in[7];
    const float* bv = (const float*)d_in[8];
    float* out = (float*)d_out;

    const size_t XN = (size_t)8192 * 1024;
    const size_t WN = (size_t)1024 * 1024;

    _Float16* ws  = (_Float16*)d_ws;
    _Float16* Xqh = ws;
    _Float16* Xkh = Xqh + XN;
    _Float16* Xvh = Xkh + XN;
    _Float16* WqT = Xvh + XN;
    _Float16* WkT = WqT + WN;
    _Float16* WvT = WkT + WN;
    _Float16* qh  = WvT + WN;
    _Float16* kh  = qh + XN;
    _Float16* vT  = kh + XN;                     // [1024 x 8192]
    _Float16* S   = vT + XN;                     // [4 x 2048 x 2048] (holds exp)
    float* rowsum = (float*)(S + (size_t)4 * 2048 * 2048);   // [8192]

    // 1. prep: convert X to f16, transpose W to f16 W^T, zero rowsum
    {
        dim3 g(8192, 4);
        prep<<<g, 256, 0, stream>>>((const float4*)Xq, Xqh,
                                    (const float4*)Xk, Xkh,
                                    (const float4*)Xv, Xvh,
                                    Wq, WqT, Wk, WkT, Wv, WvT, rowsum);
    }

    // 2. q, k, vT projections in ONE dispatch (768 blocks, 256x128 tiles)
    {
        dim3 g(8, 32, 3);
        gemm_core<0><<<g, 256, 0, stream>>>(
            Xqh, WqT, qh, bq,
            Xkh, WkT, kh, bk,
            WvT, Xvh, vT, bv,
            nullptr);
    }

    // 3. S~ = exp(q k^T / 32) f16 + atomic f32 row sums (512 blocks)
    {
        dim3 g(8, 16, 4);
        gemm_core<3><<<g, 256, 0, stream>>>(
            qh, kh, S, nullptr,
            nullptr, nullptr, nullptr, nullptr,
            nullptr, nullptr, nullptr, nullptr,
            rowsum);
    }

    // 4. out = (S~ @ v) / rowsum  (256x128 tiles, 256 blocks)
    {
        dim3 g(8, 8, 4);
        gemm_core<5><<<g, 256, 0, stream>>>(
            S, vT, out, nullptr,
            nullptr, nullptr, nullptr, nullptr,
            nullptr, nullptr, nullptr, nullptr,
            rowsum);
    }
}

// Round 2
// 341.521 us; speedup vs baseline: 1.0378x; 1.0378x over previous
//
#include <hip/hip_runtime.h>

typedef _Float16 f16x8 __attribute__((ext_vector_type(8)));
typedef _Float16 f16x4 __attribute__((ext_vector_type(4)));
typedef float f32x4 __attribute__((ext_vector_type(4)));

// Async global->LDS, 16B per lane. LDS dest must be wave-uniform base; HW adds lane*16.
__device__ __forceinline__ void lds_load16(const _Float16* g, _Float16* l) {
    __builtin_amdgcn_global_load_lds(
        (const __attribute__((address_space(1))) void*)g,
        (__attribute__((address_space(3))) void*)l,
        16, 0, 0);
}

// ---------------------------------------------------------------------------
// NT GEMM core: C[M,N] = A[M,K]*B[N,K]^T. f16 in, fp32 acc.
// 8-phase counted-vmcnt template (T3+T4+T2+T5): tile 256x256, BK=64,
// 512 thr = 8 waves (2M x 4N), wave-tile 128x64, acc[8][4].
// Per K-tile: 4 phases, each {ds_read subtile || stage -> barrier ->
// lgkmcnt(0) -> setprio(1) 16xMFMA setprio(0) -> barrier}. All 4 half-tiles
// of kt+1 staged at phases 0-1 of kt (4 gload_lds each); readiness wait is
// s_waitcnt vmcnt(4) at phase 0 (drains kt's 8 loads, keeps 4 newest in
// flight) -- never vmcnt(0) in steady state.
//
// LDS swizzle (both-sides, rule #21): LDS[row][slot16B] = G[row][slot ^
// (row&7)], achieved by pre-swizzled per-lane GLOBAL source (dest linear for
// gload_lds) and slot XOR on the ds_read side. Per-kq quarter: 16 lanes over
// 8 slots = 2-way = free.
//
// MODE 0: triple projection, z in {0,1,2}:
//   z=0: q  = Xqh@WqT^T + bq[n]   z=1: k = Xkh@WkT^T + bk[n]   (ldc=1024)
//   z=2: vT = WvT@Xvh^T + bv[m]   (ldc=8192)
// MODE 3: S~ = exp((q k^T)/32) f16 + atomic f32 row sums; z = batch
// MODE 5: out = (S~ @ v) * (1/rowsum[row]) f32 store; z = batch
// ---------------------------------------------------------------------------
template <int MODE>
__global__ __launch_bounds__(512, 2)
void gemm_core(const _Float16* A0, const _Float16* B0, void* C0, const float* b0,
               const _Float16* A1, const _Float16* B1, void* C1, const float* b1,
               const _Float16* A2, const _Float16* B2, void* C2, const float* b2,
               float* rowsum)
{
    constexpr int K   = (MODE == 5) ? 2048 : 1024;
    constexpr int LDA = (MODE == 5) ? 2048 : 1024;
    constexpr int LDB = (MODE == 5) ? 8192 : 1024;
    constexpr int NT  = K / 64;

    __shared__ __align__(16) _Float16 As[2][256 * 64];
    __shared__ __align__(16) _Float16 Bs[2][256 * 64];

    const int z = blockIdx.z;
    const int bx = blockIdx.x, by = blockIdx.y;
    const int t    = threadIdx.x;
    const int w    = t >> 6;
    const int lane = t & 63;
    const int ln   = lane & 15;
    const int kq   = lane >> 4;
    const int wm   = (w >> 2) * 128;      // warp_m in {0,1}
    const int wn   = (w & 3) * 64;        // warp_n in {0..3}

    const _Float16* A;
    const _Float16* B;
    size_t cbase = 0;
    int m0, n0;

    if (MODE == 0) {
        // grid (8,16,3); XCD = bx. z0/z1: disjoint 1024-row A strips per XCD
        // (A fetched once), B panel shared. z2: disjoint B(Xvh) strips.
        A = z == 0 ? A0 : z == 1 ? A1 : A2;
        B = z == 0 ? B0 : z == 1 ? B1 : B2;
        if (z == 2) { m0 = (by & 3) * 256;             n0 = (bx * 4 + (by >> 2)) * 256; }
        else        { m0 = (bx * 4 + (by >> 2)) * 256; n0 = (by & 3) * 256; }
    } else if (MODE == 3) {
        // grid (8,8,4); XCD = bx. 2x4 super-tile per XCD: 1MB q-strip + 1MB
        // k-strip both L2-resident.
        A = A0 + (size_t)z * 2048 * 1024;      // q slice
        B = B0 + (size_t)z * 2048 * 1024;      // k slice
        cbase = (size_t)z * 2048 * 2048;
        rowsum += z * 2048;
        m0 = ((bx & 3) * 2 + (by >> 2)) * 256;
        n0 = ((bx >> 2) * 4 + (by & 3)) * 256;
    } else {
        // grid (8,4,4); XCD = bx: 1MB S~ row-strip per XCD.
        A = A0 + (size_t)z * 2048 * 2048;      // S~ slice
        B = B0 + (size_t)z * 2048;             // vT col offset
        cbase = (size_t)z * 2048 * 1024;
        rowsum += z * 2048;
        m0 = bx * 256;
        n0 = by * 256;
    }

    // ---- staging (pre-swizzled global source, linear LDS dest) ----
    // wave w covers rows w*16 + s*8 + (lane>>3) of each 128-row half-tile;
    // global 16B-chunk = (lane&7) ^ (lane>>3)  [= slot ^ (row&7)].
    const int l3 = lane >> 3;
    const int lc = ((lane & 7) ^ l3) * 8;
    const _Float16* gA = A + (size_t)(m0 + w * 16 + l3) * LDA + lc;
    const _Float16* gB = B + (size_t)(n0 + w * 16 + l3) * LDB + lc;

    auto stA = [&](int b, int kt, int h) {
        const _Float16* g = gA + (size_t)(h * 128) * LDA + kt * 64;
        _Float16* l = As[b] + h * 8192 + w * 1024;
        lds_load16(g, l);
        lds_load16(g + (size_t)8 * LDA, l + 512);
    };
    auto stB = [&](int b, int kt, int h) {
        const _Float16* g = gB + (size_t)(h * 128) * LDB + kt * 64;
        _Float16* l = Bs[b] + h * 8192 + w * 1024;
        lds_load16(g, l);
        lds_load16(g + (size_t)8 * LDB, l + 512);
    };

    // ---- read side: slot = (kh*4 + kq) ^ (row&7), row&7 == ln&7 ----
    const int xr  = ln & 7;
    const int sk0 = ((0 + kq) ^ xr) * 8;
    const int sk1 = ((4 + kq) ^ xr) * 8;
    const int ra  = (wm + ln) * 64;
    const int rb  = (wn + ln) * 64;

    f16x8 af[4][2], bf[4][2];
    f32x4 acc[8][4] = {};

    // prologue: stage all of kt0 into buf0 (8 loads/thread)
    stA(0, 0, 0); stA(0, 0, 1); stB(0, 0, 0); stB(0, 0, 1);

    for (int kt = 0; kt < NT; kt += 2) {
#pragma unroll
        for (int hlf = 0; hlf < 2; ++hlf) {
            const int  b  = hlf;
            const int  kc = kt + hlf;
            const bool pf = (kc + 1 < NT);
            const _Float16* Ab = As[b];
            const _Float16* Bb = Bs[b];

            // ---- phase 0: stage A-halves(kt+1); vmcnt(4); quad (i0-3,j0-1) ----
            if (pf) {
                stA(b ^ 1, kc + 1, 0); stA(b ^ 1, kc + 1, 1);
                asm volatile("s_waitcnt vmcnt(4)" ::: "memory");
            } else {
                asm volatile("s_waitcnt vmcnt(0)" ::: "memory");
            }
            __builtin_amdgcn_s_barrier();
            __builtin_amdgcn_sched_barrier(0);
#pragma unroll
            for (int i = 0; i < 4; ++i) {
                af[i][0] = *(const f16x8*)(Ab + ra + i * 1024 + sk0);
                af[i][1] = *(const f16x8*)(Ab + ra + i * 1024 + sk1);
            }
#pragma unroll
            for (int j = 0; j < 2; ++j) {
                bf[j][0] = *(const f16x8*)(Bb + rb + j * 1024 + sk0);
                bf[j][1] = *(const f16x8*)(Bb + rb + j * 1024 + sk1);
            }
            asm volatile("s_waitcnt lgkmcnt(0)" ::: "memory");
            __builtin_amdgcn_sched_barrier(0);
            __builtin_amdgcn_s_setprio(1);
#pragma unroll
            for (int i = 0; i < 4; ++i)
#pragma unroll
                for (int j = 0; j < 2; ++j) {
                    acc[i][j] = __builtin_amdgcn_mfma_f32_16x16x32_f16(af[i][0], bf[j][0], acc[i][j], 0, 0, 0);
                    acc[i][j] = __builtin_amdgcn_mfma_f32_16x16x32_f16(af[i][1], bf[j][1], acc[i][j], 0, 0, 0);
                }
            __builtin_amdgcn_s_setprio(0);
            __builtin_amdgcn_s_barrier();
            __builtin_amdgcn_sched_barrier(0);

            // ---- phase 1: read bf2-3 || stage B-halves(kt+1); quad (i0-3,j2-3) ----
#pragma unroll
            for (int j = 2; j < 4; ++j) {
                bf[j][0] = *(const f16x8*)(Bb + rb + j * 1024 + sk0);
                bf[j][1] = *(const f16x8*)(Bb + rb + j * 1024 + sk1);
            }
            if (pf) { stB(b ^ 1, kc + 1, 0); stB(b ^ 1, kc + 1, 1); }
            __builtin_amdgcn_s_barrier();
            asm volatile("s_waitcnt lgkmcnt(0)" ::: "memory");
            __builtin_amdgcn_sched_barrier(0);
            __builtin_amdgcn_s_setprio(1);
#pragma unroll
            for (int i = 0; i < 4; ++i)
#pragma unroll
                for (int j = 2; j < 4; ++j) {
                    acc[i][j] = __builtin_amdgcn_mfma_f32_16x16x32_f16(af[i][0], bf[j][0], acc[i][j], 0, 0, 0);
                    acc[i][j] = __builtin_amdgcn_mfma_f32_16x16x32_f16(af[i][1], bf[j][1], acc[i][j], 0, 0, 0);
                }
            __builtin_amdgcn_s_setprio(0);
            __builtin_amdgcn_s_barrier();
            __builtin_amdgcn_sched_barrier(0);

            // ---- phase 2: read af4-7 (reuse regs); quad (i4-7,j0-1) ----
#pragma unroll
            for (int i = 0; i < 4; ++i) {
                af[i][0] = *(const f16x8*)(Ab + ra + (i + 4) * 1024 + sk0);
                af[i][1] = *(const f16x8*)(Ab + ra + (i + 4) * 1024 + sk1);
            }
            __builtin_amdgcn_s_barrier();
            asm volatile("s_waitcnt lgkmcnt(0)" ::: "memory");
            __builtin_amdgcn_sched_barrier(0);
            __builtin_amdgcn_s_setprio(1);
#pragma unroll
            for (int i = 0; i < 4; ++i)
#pragma unroll
                for (int j = 0; j < 2; ++j) {
                    acc[i + 4][j] = __builtin_amdgcn_mfma_f32_16x16x32_f16(af[i][0], bf[j][0], acc[i + 4][j], 0, 0, 0);
                    acc[i + 4][j] = __builtin_amdgcn_mfma_f32_16x16x32_f16(af[i][1], bf[j][1], acc[i + 4][j], 0, 0, 0);
                }
            __builtin_amdgcn_s_setprio(0);
            __builtin_amdgcn_s_barrier();
            __builtin_amdgcn_sched_barrier(0);

            // ---- phase 3: no reads; quad (i4-7,j2-3) ----
            __builtin_amdgcn_s_setprio(1);
#pragma unroll
            for (int i = 0; i < 4; ++i)
#pragma unroll
                for (int j = 2; j < 4; ++j) {
                    acc[i + 4][j] = __builtin_amdgcn_mfma_f32_16x16x32_f16(af[i][0], bf[j][0], acc[i + 4][j], 0, 0, 0);
                    acc[i + 4][j] = __builtin_amdgcn_mfma_f32_16x16x32_f16(af[i][1], bf[j][1], acc[i + 4][j], 0, 0, 0);
                }
            __builtin_amdgcn_s_setprio(0);
            __builtin_amdgcn_s_barrier();
            __builtin_amdgcn_sched_barrier(0);
        }
    }

    // Epilogue. C/D layout: col = lane&15, row = (lane>>4)*4 + reg.
    if (MODE == 0) {
        _Float16* Cp = (_Float16*)(z == 0 ? C0 : z == 1 ? C1 : C2);
        const float* bp = z == 0 ? b0 : z == 1 ? b1 : b2;
        const int ldc = (z == 2) ? 8192 : 1024;
#pragma unroll
        for (int i = 0; i < 8; ++i) {
            const int rbase = m0 + wm + i * 16 + kq * 4;
#pragma unroll
            for (int j = 0; j < 4; ++j) {
                const int gcol = n0 + wn + j * 16 + ln;
#pragma unroll
                for (int r = 0; r < 4; ++r) {
                    float vv = acc[i][j][r] + (z == 2 ? bp[rbase + r] : bp[gcol]);
                    Cp[(size_t)(rbase + r) * ldc + gcol] = (_Float16)vv;
                }
            }
        }
    } else if (MODE == 3) {
        _Float16* Ch = (_Float16*)C0;
#pragma unroll
        for (int i = 0; i < 8; ++i) {
            const int rbase = m0 + wm + i * 16 + kq * 4;
            float rs[4] = {0.f, 0.f, 0.f, 0.f};
#pragma unroll
            for (int j = 0; j < 4; ++j) {
                const int gcol = n0 + wn + j * 16 + ln;
#pragma unroll
                for (int r = 0; r < 4; ++r) {
                    float e = __expf(acc[i][j][r] * 0.03125f);
                    Ch[cbase + (size_t)(rbase + r) * 2048 + gcol] = (_Float16)e;
                    rs[r] += e;
                }
            }
#pragma unroll
            for (int r = 0; r < 4; ++r) {
                float s = rs[r];
                s += __shfl_xor(s, 1);
                s += __shfl_xor(s, 2);
                s += __shfl_xor(s, 4);
                s += __shfl_xor(s, 8);
                if (ln == 0) atomicAdd(&rowsum[rbase + r], s);
            }
        }
    } else {
        float* Cf = (float*)C0;
#pragma unroll
        for (int i = 0; i < 8; ++i) {
            const int rbase = m0 + wm + i * 16 + kq * 4;
            float inv[4];
#pragma unroll
            for (int r = 0; r < 4; ++r) inv[r] = 1.f / rowsum[rbase + r];
#pragma unroll
            for (int j = 0; j < 4; ++j) {
                const int gcol = n0 + wn + j * 16 + ln;
#pragma unroll
                for (int r = 0; r < 4; ++r)
                    Cf[cbase + (size_t)(rbase + r) * 1024 + gcol] = acc[i][j][r] * inv[r];
            }
        }
    }
}

// ---------------------------------------------------------------------------
// Prep kernel, ONE launch. grid (8192, 4), 256 threads:
//   y in {0,1,2}: f32->f16 convert of X_y (float4/thread); y==0,x<32 zeros rowsum.
//   y==3, x<3072: 32x32 transpose tile of W_{x/1024} -> f16 W^T.
// ---------------------------------------------------------------------------
__global__ __launch_bounds__(256)
void prep(const float4* __restrict__ x0, _Float16* __restrict__ y0,
          const float4* __restrict__ x1, _Float16* __restrict__ y1,
          const float4* __restrict__ x2, _Float16* __restrict__ y2,
          const float* __restrict__ W0, _Float16* __restrict__ T0,
          const float* __restrict__ W1, _Float16* __restrict__ T1,
          const float* __restrict__ W2, _Float16* __restrict__ T2,
          float* __restrict__ rowsum)
{
    if (blockIdx.y < 3) {
        const size_t i = (size_t)blockIdx.x * 256 + threadIdx.x;
        const float4* x = blockIdx.y == 0 ? x0 : blockIdx.y == 1 ? x1 : x2;
        _Float16*    yy = blockIdx.y == 0 ? y0 : blockIdx.y == 1 ? y1 : y2;
        float4 f = x[i];
        f16x4 o = { (_Float16)f.x, (_Float16)f.y, (_Float16)f.z, (_Float16)f.w };
        *(f16x4*)(yy + i * 4) = o;
        if (blockIdx.y == 0 && blockIdx.x < 32)
            rowsum[blockIdx.x * 256 + threadIdx.x] = 0.f;
        return;
    }
    if (blockIdx.x >= 3072) return;
    const int zz = blockIdx.x >> 10;          // which W
    const int tb = blockIdx.x & 1023;         // tile id: 32x32 grid of 32x32 tiles
    const float* W = zz == 0 ? W0 : zz == 1 ? W1 : W2;
    _Float16*   WT = zz == 0 ? T0 : zz == 1 ? T1 : T2;
    __shared__ float tile[32][33];
    const int bxs = (tb & 31) * 32;           // source col block
    const int bys = (tb >> 5) * 32;           // source row block
    const int tx = threadIdx.x & 31;
    const int ty = threadIdx.x >> 5;          // 0..7
#pragma unroll
    for (int i = ty; i < 32; i += 8)
        tile[i][tx] = W[(size_t)(bys + i) * 1024 + bxs + tx];
    __syncthreads();
#pragma unroll
    for (int i = ty; i < 32; i += 8)
        WT[(size_t)(bxs + i) * 1024 + bys + tx] = (_Float16)tile[tx][i];
}

// ---------------------------------------------------------------------------
// B=4, Lq=Lk=2048, D=1024.
// prep (cvt+transpose+zero) -> {q,k,vT} one dispatch -> S~=exp(qk^T/32)+rowsum
// -> out = S~@v / rowsum.
// ---------------------------------------------------------------------------
extern "C" void kernel_launch(void* const* d_in, const int* in_sizes, int n_in,
                              void* d_out, int out_size, void* d_ws, size_t ws_size,
                              hipStream_t stream)
{
    const float* Xq = (const float*)d_in[0];
    const float* Xk = (const float*)d_in[1];
    const float* Xv = (const float*)d_in[2];
    const float* Wq = (const float*)d_in[3];
    const float* bq = (const float*)d_in[4];
    const float* Wk = (const float*)d_in[5];
    const float* bk = (const float*)d_in[6];
    const float* Wv = (const float*)d_in[7];
    const float* bv = (const float*)d_in[8];
    float* out = (float*)d_out;

    const size_t XN = (size_t)8192 * 1024;
    const size_t WN = (size_t)1024 * 1024;

    _Float16* ws  = (_Float16*)d_ws;
    _Float16* Xqh = ws;
    _Float16* Xkh = Xqh + XN;
    _Float16* Xvh = Xkh + XN;
    _Float16* WqT = Xvh + XN;
    _Float16* WkT = WqT + WN;
    _Float16* WvT = WkT + WN;
    _Float16* qh  = WvT + WN;
    _Float16* kh  = qh + XN;
    _Float16* vT  = kh + XN;                     // [1024 x 8192]
    _Float16* S   = vT + XN;                     // [4 x 2048 x 2048] (holds exp)
    float* rowsum = (float*)(S + (size_t)4 * 2048 * 2048);   // [8192]

    // 1. prep: convert X to f16, transpose W to f16 W^T, zero rowsum
    {
        dim3 g(8192, 4);
        prep<<<g, 256, 0, stream>>>((const float4*)Xq, Xqh,
                                    (const float4*)Xk, Xkh,
                                    (const float4*)Xv, Xvh,
                                    Wq, WqT, Wk, WkT, Wv, WvT, rowsum);
    }

    // 2. q, k, vT projections in ONE dispatch (384 blocks, 256x256 tiles)
    {
        dim3 g(8, 16, 3);
        gemm_core<0><<<g, 512, 0, stream>>>(
            Xqh, WqT, qh, bq,
            Xkh, WkT, kh, bk,
            WvT, Xvh, vT, bv,
            nullptr);
    }

    // 3. S~ = exp(q k^T / 32) f16 + atomic f32 row sums (256 blocks)
    {
        dim3 g(8, 8, 4);
        gemm_core<3><<<g, 512, 0, stream>>>(
            qh, kh, S, nullptr,
            nullptr, nullptr, nullptr, nullptr,
            nullptr, nullptr, nullptr, nullptr,
            rowsum);
    }

    // 4. out = (S~ @ v) / rowsum  (256x256 tiles, 128 blocks)
    {
        dim3 g(8, 4, 4);
        gemm_core<5><<<g, 512, 0, stream>>>(
            S, vT, out, nullptr,
            nullptr, nullptr, nullptr, nullptr,
            nullptr, nullptr, nullptr, nullptr,
            rowsum);
    }
}

// Round 3
// 319.679 us; speedup vs baseline: 1.1087x; 1.0683x over previous
//
#include <hip/hip_runtime.h>

typedef _Float16 f16x8 __attribute__((ext_vector_type(8)));
typedef _Float16 f16x4 __attribute__((ext_vector_type(4)));
typedef float f32x4 __attribute__((ext_vector_type(4)));

// Async global->LDS, 16B per lane. LDS dest must be wave-uniform base; HW adds lane*16.
__device__ __forceinline__ void lds_load16(const _Float16* g, _Float16* l) {
    __builtin_amdgcn_global_load_lds(
        (const __attribute__((address_space(1))) void*)g,
        (__attribute__((address_space(3))) void*)l,
        16, 0, 0);
}

// ---------------------------------------------------------------------------
// NT GEMM core: C[M,N] = A[M,K]*B[N,K]^T. f16 in, fp32 acc.
// Template-exact 8-phase counted-vmcnt schedule (T2+T3+T4+T5):
//   tile BMxBN (256x256 or 128x256), BK=64, 512 thr = 8 waves (2M x 4N),
//   wave-tile (BM/2)x64, acc[MI][4], MI = BM/32.
// Per K-tile kc (buf b = kc&1), 4 phases, EACH phase:
//   { ds_reads for THIS phase's MFMA (issued BEFORE the leading barrier,
//     overlapping other waves' previous-phase MFMA) -> s_barrier ->
//     lgkmcnt(0) -> setprio(1) MFMA-quadrant setprio(0) -> s_barrier }.
// Staging: ALL 8 (or 6) gload_lds for K-tile kc+2 issued at phase 3 of kc,
// into buf b (its reads ended at phase 2; rendezvous barrier makes it safe),
// then s_waitcnt vmcnt(8): drains kt+1's loads (issued 4 phases earlier),
// keeps kt+2's 8 in flight -- never vmcnt(0) in steady state.
//
// LDS swizzle (both-sides, rule #21): LDS[row][slot16B] = G[row][slot ^
// (row&7)] via pre-swizzled per-lane GLOBAL source (linear gload_lds dest)
// and slot XOR on the ds_read side. 16 lanes over 8 slots = 2-way = free.
//
// MODE 0 (BM=256): triple projection, z in {0,1,2}:
//   z=0: q  = Xqh@WqT^T + bq[n]   z=1: k = Xkh@WkT^T + bk[n]   (ldc=1024)
//   z=2: vT = WvT@Xvh^T + bv[m]   (ldc=8192)
// MODE 3 (BM=256): S~ = exp((q k^T)/32) f16 + atomic f32 row sums; z = batch
// MODE 5 (BM=128): out = (S~ @ v) * (1/rowsum[row]) f32; 256 blocks (full
//   machine; old 256x256 tiling gave 128 blocks = half the CUs idle).
// ---------------------------------------------------------------------------
template <int MODE>
__global__ __launch_bounds__(512, 2)
void gemm_core(const _Float16* A0, const _Float16* B0, void* C0, const float* b0,
               const _Float16* A1, const _Float16* B1, void* C1, const float* b1,
               const _Float16* A2, const _Float16* B2, void* C2, const float* b2,
               float* rowsum)
{
    constexpr int BM  = (MODE == 5) ? 128 : 256;
    constexpr int BN  = 256;
    constexpr int K   = (MODE == 5) ? 2048 : 1024;
    constexpr int LDA = (MODE == 5) ? 2048 : 1024;
    constexpr int LDB = (MODE == 5) ? 8192 : 1024;
    constexpr int NT  = K / 64;
    constexpr int MI  = BM / 32;        // acc rows: 8 or 4
    constexpr int MH  = MI / 2;         // 4 or 2
    constexpr int LA  = BM / 64;        // A staging loads/thread: 4 or 2
    constexpr int LT  = LA + 4;         // total loads/K-tile/thread: 8 or 6

    __shared__ __align__(16) _Float16 As[2][BM * 64];
    __shared__ __align__(16) _Float16 Bs[2][BN * 64];

    const int z_ = blockIdx.z;
    const int bx = blockIdx.x, by = blockIdx.y;
    const int t    = threadIdx.x;
    const int w    = t >> 6;
    const int lane = t & 63;
    const int ln   = lane & 15;
    const int kq   = lane >> 4;
    const int wm   = (w >> 2) * (BM / 2);
    const int wn   = (w & 3) * 64;

    const _Float16* A;
    const _Float16* B;
    size_t cbase = 0;
    int m0, n0, z = z_;

    if (MODE == 0) {
        // grid (8,16,3); XCD = bx. z0/z1: disjoint 1024-row A strips per XCD.
        A = z == 0 ? A0 : z == 1 ? A1 : A2;
        B = z == 0 ? B0 : z == 1 ? B1 : B2;
        if (z == 2) { m0 = (by & 3) * 256;             n0 = (bx * 4 + (by >> 2)) * 256; }
        else        { m0 = (bx * 4 + (by >> 2)) * 256; n0 = (by & 3) * 256; }
    } else if (MODE == 3) {
        // grid (8,8,4); XCD = bx. 2x4 super-tile per XCD.
        A = A0 + (size_t)z * 2048 * 1024;      // q slice
        B = B0 + (size_t)z * 2048 * 1024;      // k slice
        cbase = (size_t)z * 2048 * 2048;
        rowsum += z * 2048;
        m0 = ((bx & 3) * 2 + (by >> 2)) * 256;
        n0 = ((bx >> 2) * 4 + (by & 3)) * 256;
    } else {
        // grid (8,16,2); XCD = bx = (zpar<<2)|n-tile: each XCD owns one
        // 256-col vT slice x 2 z (2 MB, L2-resident); S~ streamed once.
        z = (blockIdx.z << 1) | (bx >> 2);
        A = A0 + (size_t)z * 2048 * 2048;      // S~ slice
        B = B0 + (size_t)z * 2048;             // vT col offset
        cbase = (size_t)z * 2048 * 1024;
        rowsum += z * 2048;
        m0 = by * 128;
        n0 = (bx & 3) * 256;
    }

    // ---- staging (pre-swizzled global source, linear LDS dest) ----
    // thread t: row r6 = t>>3 within each 64-row block s; global 16B-chunk
    // = (t&7) ^ (r6&7)  [LDS[r][c] = G[r][c ^ (r&7)]].
    const int r6 = t >> 3;
    const int cw = ((t & 7) ^ (r6 & 7)) * 8;
    const _Float16* gA = A + (size_t)(m0 + r6) * LDA + cw;
    const _Float16* gB = B + (size_t)(n0 + r6) * LDB + cw;

    auto stage = [&](int b, int kt) {
#pragma unroll
        for (int s = 0; s < LA; ++s)
            lds_load16(gA + (size_t)(s * 64) * LDA + kt * 64, As[b] + s * 4096 + w * 512);
#pragma unroll
        for (int s = 0; s < 4; ++s)
            lds_load16(gB + (size_t)(s * 64) * LDB + kt * 64, Bs[b] + s * 4096 + w * 512);
    };

    // ---- read side: slot = (kh*4 + kq) ^ (row&7), row&7 == ln&7 ----
    const int xr  = ln & 7;
    const int sk0 = ((0 + kq) ^ xr) * 8;
    const int sk1 = ((4 + kq) ^ xr) * 8;
    const int ra  = (wm + ln) * 64;
    const int rb  = (wn + ln) * 64;

    f16x8 af[MH][2], bf[4][2];
    f32x4 acc[MI][4] = {};

    // prologue: stage kt0->buf0, kt1->buf1; drain kt0 (keep kt1 in flight)
    stage(0, 0);
    stage(1, 1);
    if constexpr (MODE == 5) asm volatile("s_waitcnt vmcnt(6)" ::: "memory");
    else                     asm volatile("s_waitcnt vmcnt(8)" ::: "memory");
    __builtin_amdgcn_s_barrier();
    __builtin_amdgcn_sched_barrier(0);

#pragma unroll 2
    for (int kc = 0; kc < NT; ++kc) {
        const int b = kc & 1;
        const _Float16* Ab = As[b];
        const _Float16* Bb = Bs[b];

        // ---- phase 0: reads af-lo + bf[0,1]; MFMA (i-lo, j0-1) ----
#pragma unroll
        for (int i = 0; i < MH; ++i) {
            af[i][0] = *(const f16x8*)(Ab + ra + i * 1024 + sk0);
            af[i][1] = *(const f16x8*)(Ab + ra + i * 1024 + sk1);
        }
#pragma unroll
        for (int j = 0; j < 2; ++j) {
            bf[j][0] = *(const f16x8*)(Bb + rb + j * 1024 + sk0);
            bf[j][1] = *(const f16x8*)(Bb + rb + j * 1024 + sk1);
        }
        __builtin_amdgcn_s_barrier();
        asm volatile("s_waitcnt lgkmcnt(0)" ::: "memory");
        __builtin_amdgcn_sched_barrier(0);
        __builtin_amdgcn_s_setprio(1);
#pragma unroll
        for (int i = 0; i < MH; ++i)
#pragma unroll
            for (int j = 0; j < 2; ++j) {
                acc[i][j] = __builtin_amdgcn_mfma_f32_16x16x32_f16(af[i][0], bf[j][0], acc[i][j], 0, 0, 0);
                acc[i][j] = __builtin_amdgcn_mfma_f32_16x16x32_f16(af[i][1], bf[j][1], acc[i][j], 0, 0, 0);
            }
        __builtin_amdgcn_s_setprio(0);
        __builtin_amdgcn_s_barrier();
        __builtin_amdgcn_sched_barrier(0);

        // ---- phase 1: reads bf[2,3]; MFMA (i-lo, j2-3) ----
#pragma unroll
        for (int j = 2; j < 4; ++j) {
            bf[j][0] = *(const f16x8*)(Bb + rb + j * 1024 + sk0);
            bf[j][1] = *(const f16x8*)(Bb + rb + j * 1024 + sk1);
        }
        __builtin_amdgcn_s_barrier();
        asm volatile("s_waitcnt lgkmcnt(0)" ::: "memory");
        __builtin_amdgcn_sched_barrier(0);
        __builtin_amdgcn_s_setprio(1);
#pragma unroll
        for (int i = 0; i < MH; ++i)
#pragma unroll
            for (int j = 2; j < 4; ++j) {
                acc[i][j] = __builtin_amdgcn_mfma_f32_16x16x32_f16(af[i][0], bf[j][0], acc[i][j], 0, 0, 0);
                acc[i][j] = __builtin_amdgcn_mfma_f32_16x16x32_f16(af[i][1], bf[j][1], acc[i][j], 0, 0, 0);
            }
        __builtin_amdgcn_s_setprio(0);
        __builtin_amdgcn_s_barrier();
        __builtin_amdgcn_sched_barrier(0);

        // ---- phase 2: reads af-hi (reuse regs); MFMA (i-hi, j0-1) ----
#pragma unroll
        for (int i = 0; i < MH; ++i) {
            af[i][0] = *(const f16x8*)(Ab + ra + (i + MH) * 1024 + sk0);
            af[i][1] = *(const f16x8*)(Ab + ra + (i + MH) * 1024 + sk1);
        }
        __builtin_amdgcn_s_barrier();
        asm volatile("s_waitcnt lgkmcnt(0)" ::: "memory");
        __builtin_amdgcn_sched_barrier(0);
        __builtin_amdgcn_s_setprio(1);
#pragma unroll
        for (int i = 0; i < MH; ++i)
#pragma unroll
            for (int j = 0; j < 2; ++j) {
                acc[i + MH][j] = __builtin_amdgcn_mfma_f32_16x16x32_f16(af[i][0], bf[j][0], acc[i + MH][j], 0, 0, 0);
                acc[i + MH][j] = __builtin_amdgcn_mfma_f32_16x16x32_f16(af[i][1], bf[j][1], acc[i + MH][j], 0, 0, 0);
            }
        __builtin_amdgcn_s_setprio(0);
        __builtin_amdgcn_s_barrier();
        __builtin_amdgcn_sched_barrier(0);

        // ---- phase 3: stage kt+2 -> buf b (reads of b ended at ph2);
        //      counted drain of kt+1's loads; MFMA (i-hi, j2-3) ----
        if (kc + 2 < NT) {
            stage(b, kc + 2);
            if constexpr (MODE == 5) asm volatile("s_waitcnt vmcnt(6)" ::: "memory");
            else                     asm volatile("s_waitcnt vmcnt(8)" ::: "memory");
        } else if (kc + 1 < NT) {
            asm volatile("s_waitcnt vmcnt(0)" ::: "memory");
        }
        __builtin_amdgcn_s_barrier();
        __builtin_amdgcn_sched_barrier(0);
        __builtin_amdgcn_s_setprio(1);
#pragma unroll
        for (int i = 0; i < MH; ++i)
#pragma unroll
            for (int j = 2; j < 4; ++j) {
                acc[i + MH][j] = __builtin_amdgcn_mfma_f32_16x16x32_f16(af[i][0], bf[j][0], acc[i + MH][j], 0, 0, 0);
                acc[i + MH][j] = __builtin_amdgcn_mfma_f32_16x16x32_f16(af[i][1], bf[j][1], acc[i + MH][j], 0, 0, 0);
            }
        __builtin_amdgcn_s_setprio(0);
        __builtin_amdgcn_s_barrier();
        __builtin_amdgcn_sched_barrier(0);
    }

    // Epilogue. C/D layout: col = lane&15, row = (lane>>4)*4 + reg.
    if (MODE == 0) {
        _Float16* Cp = (_Float16*)(z == 0 ? C0 : z == 1 ? C1 : C2);
        const float* bp = z == 0 ? b0 : z == 1 ? b1 : b2;
        const int ldc = (z == 2) ? 8192 : 1024;
#pragma unroll
        for (int i = 0; i < MI; ++i) {
            const int rbase = m0 + wm + i * 16 + kq * 4;
#pragma unroll
            for (int j = 0; j < 4; ++j) {
                const int gcol = n0 + wn + j * 16 + ln;
#pragma unroll
                for (int r = 0; r < 4; ++r) {
                    float vv = acc[i][j][r] + (z == 2 ? bp[rbase + r] : bp[gcol]);
                    Cp[(size_t)(rbase + r) * ldc + gcol] = (_Float16)vv;
                }
            }
        }
    } else if (MODE == 3) {
        _Float16* Ch = (_Float16*)C0;
#pragma unroll
        for (int i = 0; i < MI; ++i) {
            const int rbase = m0 + wm + i * 16 + kq * 4;
            float rs[4] = {0.f, 0.f, 0.f, 0.f};
#pragma unroll
            for (int j = 0; j < 4; ++j) {
                const int gcol = n0 + wn + j * 16 + ln;
#pragma unroll
                for (int r = 0; r < 4; ++r) {
                    float e = __expf(acc[i][j][r] * 0.03125f);
                    Ch[cbase + (size_t)(rbase + r) * 2048 + gcol] = (_Float16)e;
                    rs[r] += e;
                }
            }
#pragma unroll
            for (int r = 0; r < 4; ++r) {
                float s = rs[r];
                s += __shfl_xor(s, 1);
                s += __shfl_xor(s, 2);
                s += __shfl_xor(s, 4);
                s += __shfl_xor(s, 8);
                if (ln == 0) atomicAdd(&rowsum[rbase + r], s);
            }
        }
    } else {
        float* Cf = (float*)C0;
#pragma unroll
        for (int i = 0; i < MI; ++i) {
            const int rbase = m0 + wm + i * 16 + kq * 4;
            float inv[4];
#pragma unroll
            for (int r = 0; r < 4; ++r) inv[r] = 1.f / rowsum[rbase + r];
#pragma unroll
            for (int j = 0; j < 4; ++j) {
                const int gcol = n0 + wn + j * 16 + ln;
#pragma unroll
                for (int r = 0; r < 4; ++r)
                    Cf[cbase + (size_t)(rbase + r) * 1024 + gcol] = acc[i][j][r] * inv[r];
            }
        }
    }
}

// ---------------------------------------------------------------------------
// Prep kernel, ONE launch. grid (8192, 4), 256 threads:
//   y in {0,1,2}: f32->f16 convert of X_y (float4/thread); y==0,x<32 zeros rowsum.
//   y==3, x<3072: 32x32 transpose tile of W_{x/1024} -> f16 W^T.
// ---------------------------------------------------------------------------
__global__ __launch_bounds__(256)
void prep(const float4* __restrict__ x0, _Float16* __restrict__ y0,
          const float4* __restrict__ x1, _Float16* __restrict__ y1,
          const float4* __restrict__ x2, _Float16* __restrict__ y2,
          const float* __restrict__ W0, _Float16* __restrict__ T0,
          const float* __restrict__ W1, _Float16* __restrict__ T1,
          const float* __restrict__ W2, _Float16* __restrict__ T2,
          float* __restrict__ rowsum)
{
    if (blockIdx.y < 3) {
        const size_t i = (size_t)blockIdx.x * 256 + threadIdx.x;
        const float4* x = blockIdx.y == 0 ? x0 : blockIdx.y == 1 ? x1 : x2;
        _Float16*    yy = blockIdx.y == 0 ? y0 : blockIdx.y == 1 ? y1 : y2;
        float4 f = x[i];
        f16x4 o = { (_Float16)f.x, (_Float16)f.y, (_Float16)f.z, (_Float16)f.w };
        *(f16x4*)(yy + i * 4) = o;
        if (blockIdx.y == 0 && blockIdx.x < 32)
            rowsum[blockIdx.x * 256 + threadIdx.x] = 0.f;
        return;
    }
    if (blockIdx.x >= 3072) return;
    const int zz = blockIdx.x >> 10;          // which W
    const int tb = blockIdx.x & 1023;         // tile id: 32x32 grid of 32x32 tiles
    const float* W = zz == 0 ? W0 : zz == 1 ? W1 : W2;
    _Float16*   WT = zz == 0 ? T0 : zz == 1 ? T1 : T2;
    __shared__ float tile[32][33];
    const int bxs = (tb & 31) * 32;           // source col block
    const int bys = (tb >> 5) * 32;           // source row block
    const int tx = threadIdx.x & 31;
    const int ty = threadIdx.x >> 5;          // 0..7
#pragma unroll
    for (int i = ty; i < 32; i += 8)
        tile[i][tx] = W[(size_t)(bys + i) * 1024 + bxs + tx];
    __syncthreads();
#pragma unroll
    for (int i = ty; i < 32; i += 8)
        WT[(size_t)(bxs + i) * 1024 + bys + tx] = (_Float16)tile[tx][i];
}

// ---------------------------------------------------------------------------
// B=4, Lq=Lk=2048, D=1024.
// prep (cvt+transpose+zero) -> {q,k,vT} one dispatch -> S~=exp(qk^T/32)+rowsum
// -> out = S~@v / rowsum.
// ---------------------------------------------------------------------------
extern "C" void kernel_launch(void* const* d_in, const int* in_sizes, int n_in,
                              void* d_out, int out_size, void* d_ws, size_t ws_size,
                              hipStream_t stream)
{
    const float* Xq = (const float*)d_in[0];
    const float* Xk = (const float*)d_in[1];
    const float* Xv = (const float*)d_in[2];
    const float* Wq = (const float*)d_in[3];
    const float* bq = (const float*)d_in[4];
    const float* Wk = (const float*)d_in[5];
    const float* bk = (const float*)d_in[6];
    const float* Wv = (const float*)d_in[7];
    const float* bv = (const float*)d_in[8];
    float* out = (float*)d_out;

    const size_t XN = (size_t)8192 * 1024;
    const size_t WN = (size_t)1024 * 1024;

    _Float16* ws  = (_Float16*)d_ws;
    _Float16* Xqh = ws;
    _Float16* Xkh = Xqh + XN;
    _Float16* Xvh = Xkh + XN;
    _Float16* WqT = Xvh + XN;
    _Float16* WkT = WqT + WN;
    _Float16* WvT = WkT + WN;
    _Float16* qh  = WvT + WN;
    _Float16* kh  = qh + XN;
    _Float16* vT  = kh + XN;                     // [1024 x 8192]
    _Float16* S   = vT + XN;                     // [4 x 2048 x 2048] (holds exp)
    float* rowsum = (float*)(S + (size_t)4 * 2048 * 2048);   // [8192]

    // 1. prep: convert X to f16, transpose W to f16 W^T, zero rowsum
    {
        dim3 g(8192, 4);
        prep<<<g, 256, 0, stream>>>((const float4*)Xq, Xqh,
                                    (const float4*)Xk, Xkh,
                                    (const float4*)Xv, Xvh,
                                    Wq, WqT, Wk, WkT, Wv, WvT, rowsum);
    }

    // 2. q, k, vT projections in ONE dispatch (384 blocks, 256x256 tiles)
    {
        dim3 g(8, 16, 3);
        gemm_core<0><<<g, 512, 0, stream>>>(
            Xqh, WqT, qh, bq,
            Xkh, WkT, kh, bk,
            WvT, Xvh, vT, bv,
            nullptr);
    }

    // 3. S~ = exp(q k^T / 32) f16 + atomic f32 row sums (256 blocks)
    {
        dim3 g(8, 8, 4);
        gemm_core<3><<<g, 512, 0, stream>>>(
            qh, kh, S, nullptr,
            nullptr, nullptr, nullptr, nullptr,
            nullptr, nullptr, nullptr, nullptr,
            rowsum);
    }

    // 4. out = (S~ @ v) / rowsum  (128x256 tiles, 256 blocks = full machine)
    {
        dim3 g(8, 16, 2);
        gemm_core<5><<<g, 512, 0, stream>>>(
            S, vT, out, nullptr,
            nullptr, nullptr, nullptr, nullptr,
            nullptr, nullptr, nullptr, nullptr,
            rowsum);
    }
}

// Round 4
// 313.198 us; speedup vs baseline: 1.1316x; 1.0207x over previous
//
#include <hip/hip_runtime.h>

typedef _Float16 f16x8 __attribute__((ext_vector_type(8)));
typedef _Float16 f16x4 __attribute__((ext_vector_type(4)));
typedef float f32x4 __attribute__((ext_vector_type(4)));
typedef int   v4i   __attribute__((ext_vector_type(4)));

// Async global->LDS, 16B per lane. LDS dest must be wave-uniform base; HW adds lane*16.
__device__ __forceinline__ void lds_load16(const _Float16* g, _Float16* l) {
    __builtin_amdgcn_global_load_lds(
        (const __attribute__((address_space(1))) void*)g,
        (__attribute__((address_space(3))) void*)l,
        16, 0, 0);
}

// Inline-asm LDS read, 16B at byte address a (AS(3) offset). Deliberately NO
// "memory" clobber and not a C-level load of As/Bs: hides the gload_lds->ds_read
// alias edge from the compiler so it cannot insert s_waitcnt vmcnt(0) before
// the reads (which would drain the counted-vmcnt pipeline every K-tile).
// Ordering is handled explicitly: lgkmcnt(0)+sched_barrier(0) before MFMA use
// (rule #18), rendezvous barriers for WAR on buffer reuse.
__device__ __forceinline__ f16x8 ldsr(unsigned a) {
    v4i r;
    asm volatile("ds_read_b128 %0, %1" : "=v"(r) : "v"(a));
    return __builtin_bit_cast(f16x8, r);
}

// ---------------------------------------------------------------------------
// NT GEMM core: C[M,N] = A[M,K]*B[N,K]^T. f16 in, fp32 acc.
// 8-phase counted-vmcnt schedule (T2+T3+T4+T5): tile BMxBN (256x256 or
// 128x256), BK=64, 512 thr = 8 waves (2M x 4N), wave-tile (BM/2)x64,
// acc[MI][4]. Per K-tile kc (buf b=kc&1), 4 phases, each:
//   { asm ds_reads for THIS phase -> s_barrier -> lgkmcnt(0) ->
//     setprio(1) MFMA-quadrant setprio(0) -> s_barrier }.
// Staging: all loads for kc+2 issued at phase 3 of kc into buf b (buf b's
// reads ended at phase 2; barrier rendezvous makes the WAR safe), then
// s_waitcnt vmcnt(8) drains kc+1's loads (issued 4 phases earlier) while
// keeping kc+2's in flight -- never vmcnt(0) in steady state.
//
// LDS swizzle (both-sides, rule #21): LDS[row][slot16B] = G[row][slot ^
// (row&7)] via pre-swizzled per-lane GLOBAL source (linear gload_lds dest)
// and slot XOR on the read side. 16 lanes over 8 slots = 2-way = free.
//
// MODE 0 (BM=256): triple projection, z in {0,1,2}:
//   z=0: q  = Xqh@WqT^T + bq[n]   z=1: k = Xkh@WkT^T + bk[n]   (ldc=1024)
//   z=2: vT = WvT@Xvh^T + bv[m]   (ldc=8192)
// MODE 3 (BM=256): S~ = exp((q k^T)/32) f16 + atomic f32 row sums; z = batch
// MODE 5 (BM=128): out = (S~ @ v) * (1/rowsum[row]) f32; 256 blocks.
// ---------------------------------------------------------------------------
template <int MODE>
__global__ __launch_bounds__(512, 2)
void gemm_core(const _Float16* A0, const _Float16* B0, void* C0, const float* b0,
               const _Float16* A1, const _Float16* B1, void* C1, const float* b1,
               const _Float16* A2, const _Float16* B2, void* C2, const float* b2,
               float* rowsum)
{
    constexpr int BM  = (MODE == 5) ? 128 : 256;
    constexpr int K   = (MODE == 5) ? 2048 : 1024;
    constexpr int LDA = (MODE == 5) ? 2048 : 1024;
    constexpr int LDB = (MODE == 5) ? 8192 : 1024;
    constexpr int NT  = K / 64;
    constexpr int MI  = BM / 32;        // acc rows: 8 or 4
    constexpr int MH  = MI / 2;         // 4 or 2
    constexpr int LA  = BM / 64;        // A staging loads/thread: 4 or 2

    __shared__ __align__(16) _Float16 As[2][BM * 64];
    __shared__ __align__(16) _Float16 Bs[2][256 * 64];

    const int z_ = blockIdx.z;
    const int bx = blockIdx.x, by = blockIdx.y;
    const int t    = threadIdx.x;
    const int w    = t >> 6;
    const int lane = t & 63;
    const int ln   = lane & 15;
    const int kq   = lane >> 4;
    const int wm   = (w >> 2) * (BM / 2);
    const int wn   = (w & 3) * 64;

    const _Float16* A;
    const _Float16* B;
    size_t cbase = 0;
    int m0, n0, z = z_;

    if (MODE == 0) {
        // grid (8,16,3); XCD = bx. z0/z1: disjoint 1024-row A strips per XCD.
        A = z == 0 ? A0 : z == 1 ? A1 : A2;
        B = z == 0 ? B0 : z == 1 ? B1 : B2;
        if (z == 2) { m0 = (by & 3) * 256;             n0 = (bx * 4 + (by >> 2)) * 256; }
        else        { m0 = (bx * 4 + (by >> 2)) * 256; n0 = (by & 3) * 256; }
    } else if (MODE == 3) {
        // grid (8,8,4); XCD = bx. 2x4 super-tile per XCD.
        A = A0 + (size_t)z * 2048 * 1024;      // q slice
        B = B0 + (size_t)z * 2048 * 1024;      // k slice
        cbase = (size_t)z * 2048 * 2048;
        rowsum += z * 2048;
        m0 = ((bx & 3) * 2 + (by >> 2)) * 256;
        n0 = ((bx >> 2) * 4 + (by & 3)) * 256;
    } else {
        // grid (8,16,2); XCD = bx = (zpar<<2)|n-tile: each XCD owns one
        // 256-col vT slice x 2 z (2 MB, L2-resident); S~ streamed once.
        z = (blockIdx.z << 1) | (bx >> 2);
        A = A0 + (size_t)z * 2048 * 2048;      // S~ slice
        B = B0 + (size_t)z * 2048;             // vT col offset
        cbase = (size_t)z * 2048 * 1024;
        rowsum += z * 2048;
        m0 = by * 128;
        n0 = (bx & 3) * 256;
    }

    // ---- staging (pre-swizzled global source, linear LDS dest) ----
    // thread t: row r6 = t>>3 within each 64-row block s; global 16B-chunk
    // = (t&7) ^ (r6&7)  [LDS[r][c] = G[r][c ^ (r&7)]].
    const int r6 = t >> 3;
    const int cw = ((t & 7) ^ (r6 & 7)) * 8;
    const _Float16* gA = A + (size_t)(m0 + r6) * LDA + cw;
    const _Float16* gB = B + (size_t)(n0 + r6) * LDB + cw;

    auto stage = [&](int b, int kt) {
#pragma unroll
        for (int s = 0; s < LA; ++s)
            lds_load16(gA + (size_t)(s * 64) * LDA + kt * 64, As[b] + s * 4096 + w * 512);
#pragma unroll
        for (int s = 0; s < 4; ++s)
            lds_load16(gB + (size_t)(s * 64) * LDB + kt * 64, Bs[b] + s * 4096 + w * 512);
    };

    // ---- read side byte addresses (AS(3) offsets) ----
    // element index: row*64 + slot, slot = (kh*4+kq) ^ (ln&7); bytes = 2x.
    const int xr  = ln & 7;
    const int sk0 = ((0 + kq) ^ xr) * 8;
    const int sk1 = ((4 + kq) ^ xr) * 8;
    const int ra  = (wm + ln) * 64;
    const int rb  = (wn + ln) * 64;

    const unsigned uA0 = (unsigned)(uintptr_t)(__attribute__((address_space(3))) _Float16*)&As[0][0];
    const unsigned uA1 = (unsigned)(uintptr_t)(__attribute__((address_space(3))) _Float16*)&As[1][0];
    const unsigned uB0 = (unsigned)(uintptr_t)(__attribute__((address_space(3))) _Float16*)&Bs[0][0];
    const unsigned uB1 = (unsigned)(uintptr_t)(__attribute__((address_space(3))) _Float16*)&Bs[1][0];
    // [buf][kh] base addrs for A-row/B-row fragment reads
    const unsigned aA[2][2] = { { uA0 + 2u * (ra + sk0), uA0 + 2u * (ra + sk1) },
                                { uA1 + 2u * (ra + sk0), uA1 + 2u * (ra + sk1) } };
    const unsigned aB[2][2] = { { uB0 + 2u * (rb + sk0), uB0 + 2u * (rb + sk1) },
                                { uB1 + 2u * (rb + sk0), uB1 + 2u * (rb + sk1) } };

    f16x8 af[MH][2], bf[4][2];
    f32x4 acc[MI][4] = {};

    // prologue: stage kt0->buf0, kt1->buf1; drain kt0 (keep kt1 in flight)
    stage(0, 0);
    stage(1, 1);
    if constexpr (MODE == 5) asm volatile("s_waitcnt vmcnt(6)" ::: "memory");
    else                     asm volatile("s_waitcnt vmcnt(8)" ::: "memory");
    __builtin_amdgcn_s_barrier();
    __builtin_amdgcn_sched_barrier(0);

#pragma unroll 2
    for (int kc = 0; kc < NT; ++kc) {
        const int b = kc & 1;

        // ---- phase 0: reads af-lo + bf[0,1]; MFMA (i-lo, j0-1) ----
#pragma unroll
        for (int i = 0; i < MH; ++i) {
            af[i][0] = ldsr(aA[b][0] + i * 2048);
            af[i][1] = ldsr(aA[b][1] + i * 2048);
        }
#pragma unroll
        for (int j = 0; j < 2; ++j) {
            bf[j][0] = ldsr(aB[b][0] + j * 2048);
            bf[j][1] = ldsr(aB[b][1] + j * 2048);
        }
        __builtin_amdgcn_s_barrier();
        asm volatile("s_waitcnt lgkmcnt(0)" ::: "memory");
        __builtin_amdgcn_sched_barrier(0);
        __builtin_amdgcn_s_setprio(1);
#pragma unroll
        for (int i = 0; i < MH; ++i)
#pragma unroll
            for (int j = 0; j < 2; ++j) {
                acc[i][j] = __builtin_amdgcn_mfma_f32_16x16x32_f16(af[i][0], bf[j][0], acc[i][j], 0, 0, 0);
                acc[i][j] = __builtin_amdgcn_mfma_f32_16x16x32_f16(af[i][1], bf[j][1], acc[i][j], 0, 0, 0);
            }
        __builtin_amdgcn_s_setprio(0);
        __builtin_amdgcn_s_barrier();
        __builtin_amdgcn_sched_barrier(0);

        // ---- phase 1: reads bf[2,3]; MFMA (i-lo, j2-3) ----
#pragma unroll
        for (int j = 2; j < 4; ++j) {
            bf[j][0] = ldsr(aB[b][0] + j * 2048);
            bf[j][1] = ldsr(aB[b][1] + j * 2048);
        }
        __builtin_amdgcn_s_barrier();
        asm volatile("s_waitcnt lgkmcnt(0)" ::: "memory");
        __builtin_amdgcn_sched_barrier(0);
        __builtin_amdgcn_s_setprio(1);
#pragma unroll
        for (int i = 0; i < MH; ++i)
#pragma unroll
            for (int j = 2; j < 4; ++j) {
                acc[i][j] = __builtin_amdgcn_mfma_f32_16x16x32_f16(af[i][0], bf[j][0], acc[i][j], 0, 0, 0);
                acc[i][j] = __builtin_amdgcn_mfma_f32_16x16x32_f16(af[i][1], bf[j][1], acc[i][j], 0, 0, 0);
            }
        __builtin_amdgcn_s_setprio(0);
        __builtin_amdgcn_s_barrier();
        __builtin_amdgcn_sched_barrier(0);

        // ---- phase 2: reads af-hi (reuse regs); MFMA (i-hi, j0-1) ----
#pragma unroll
        for (int i = 0; i < MH; ++i) {
            af[i][0] = ldsr(aA[b][0] + (i + MH) * 2048);
            af[i][1] = ldsr(aA[b][1] + (i + MH) * 2048);
        }
        __builtin_amdgcn_s_barrier();
        asm volatile("s_waitcnt lgkmcnt(0)" ::: "memory");
        __builtin_amdgcn_sched_barrier(0);
        __builtin_amdgcn_s_setprio(1);
#pragma unroll
        for (int i = 0; i < MH; ++i)
#pragma unroll
            for (int j = 0; j < 2; ++j) {
                acc[i + MH][j] = __builtin_amdgcn_mfma_f32_16x16x32_f16(af[i][0], bf[j][0], acc[i + MH][j], 0, 0, 0);
                acc[i + MH][j] = __builtin_amdgcn_mfma_f32_16x16x32_f16(af[i][1], bf[j][1], acc[i + MH][j], 0, 0, 0);
            }
        __builtin_amdgcn_s_setprio(0);
        __builtin_amdgcn_s_barrier();
        __builtin_amdgcn_sched_barrier(0);

        // ---- phase 3: stage kt+2 -> buf b (reads of b ended at ph2);
        //      counted drain of kt+1's loads; MFMA (i-hi, j2-3) ----
        if (kc + 2 < NT) {
            stage(b, kc + 2);
            if constexpr (MODE == 5) asm volatile("s_waitcnt vmcnt(6)" ::: "memory");
            else                     asm volatile("s_waitcnt vmcnt(8)" ::: "memory");
        } else if (kc + 1 < NT) {
            asm volatile("s_waitcnt vmcnt(0)" ::: "memory");
        }
        __builtin_amdgcn_s_barrier();
        __builtin_amdgcn_sched_barrier(0);
        __builtin_amdgcn_s_setprio(1);
#pragma unroll
        for (int i = 0; i < MH; ++i)
#pragma unroll
            for (int j = 2; j < 4; ++j) {
                acc[i + MH][j] = __builtin_amdgcn_mfma_f32_16x16x32_f16(af[i][0], bf[j][0], acc[i + MH][j], 0, 0, 0);
                acc[i + MH][j] = __builtin_amdgcn_mfma_f32_16x16x32_f16(af[i][1], bf[j][1], acc[i + MH][j], 0, 0, 0);
            }
        __builtin_amdgcn_s_setprio(0);
        __builtin_amdgcn_s_barrier();
        __builtin_amdgcn_sched_barrier(0);
    }

    // Epilogue. C/D layout: col = lane&15, row = (lane>>4)*4 + reg.
    if (MODE == 0) {
        _Float16* Cp = (_Float16*)(z == 0 ? C0 : z == 1 ? C1 : C2);
        const float* bp = z == 0 ? b0 : z == 1 ? b1 : b2;
        const int ldc = (z == 2) ? 8192 : 1024;
#pragma unroll
        for (int i = 0; i < MI; ++i) {
            const int rbase = m0 + wm + i * 16 + kq * 4;
#pragma unroll
            for (int j = 0; j < 4; ++j) {
                const int gcol = n0 + wn + j * 16 + ln;
#pragma unroll
                for (int r = 0; r < 4; ++r) {
                    float vv = acc[i][j][r] + (z == 2 ? bp[rbase + r] : bp[gcol]);
                    Cp[(size_t)(rbase + r) * ldc + gcol] = (_Float16)vv;
                }
            }
        }
    } else if (MODE == 3) {
        _Float16* Ch = (_Float16*)C0;
#pragma unroll
        for (int i = 0; i < MI; ++i) {
            const int rbase = m0 + wm + i * 16 + kq * 4;
            float rs[4] = {0.f, 0.f, 0.f, 0.f};
#pragma unroll
            for (int j = 0; j < 4; ++j) {
                const int gcol = n0 + wn + j * 16 + ln;
#pragma unroll
                for (int r = 0; r < 4; ++r) {
                    float e = __expf(acc[i][j][r] * 0.03125f);
                    Ch[cbase + (size_t)(rbase + r) * 2048 + gcol] = (_Float16)e;
                    rs[r] += e;
                }
            }
#pragma unroll
            for (int r = 0; r < 4; ++r) {
                float s = rs[r];
                s += __shfl_xor(s, 1);
                s += __shfl_xor(s, 2);
                s += __shfl_xor(s, 4);
                s += __shfl_xor(s, 8);
                if (ln == 0) atomicAdd(&rowsum[rbase + r], s);
            }
        }
    } else {
        float* Cf = (float*)C0;
#pragma unroll
        for (int i = 0; i < MI; ++i) {
            const int rbase = m0 + wm + i * 16 + kq * 4;
            float inv[4];
#pragma unroll
            for (int r = 0; r < 4; ++r) inv[r] = 1.f / rowsum[rbase + r];
#pragma unroll
            for (int j = 0; j < 4; ++j) {
                const int gcol = n0 + wn + j * 16 + ln;
#pragma unroll
                for (int r = 0; r < 4; ++r)
                    Cf[cbase + (size_t)(rbase + r) * 1024 + gcol] = acc[i][j][r] * inv[r];
            }
        }
    }
}

// ---------------------------------------------------------------------------
// Prep kernel, ONE launch. grid (8192, 4), 256 threads:
//   y in {0,1,2}: f32->f16 convert of X_y (float4/thread); y==0,x<32 zeros rowsum.
//   y==3, x<3072: 32x32 transpose tile of W_{x/1024} -> f16 W^T.
// ---------------------------------------------------------------------------
__global__ __launch_bounds__(256)
void prep(const float4* __restrict__ x0, _Float16* __restrict__ y0,
          const float4* __restrict__ x1, _Float16* __restrict__ y1,
          const float4* __restrict__ x2, _Float16* __restrict__ y2,
          const float* __restrict__ W0, _Float16* __restrict__ T0,
          const float* __restrict__ W1, _Float16* __restrict__ T1,
          const float* __restrict__ W2, _Float16* __restrict__ T2,
          float* __restrict__ rowsum)
{
    if (blockIdx.y < 3) {
        const size_t i = (size_t)blockIdx.x * 256 + threadIdx.x;
        const float4* x = blockIdx.y == 0 ? x0 : blockIdx.y == 1 ? x1 : x2;
        _Float16*    yy = blockIdx.y == 0 ? y0 : blockIdx.y == 1 ? y1 : y2;
        float4 f = x[i];
        f16x4 o = { (_Float16)f.x, (_Float16)f.y, (_Float16)f.z, (_Float16)f.w };
        *(f16x4*)(yy + i * 4) = o;
        if (blockIdx.y == 0 && blockIdx.x < 32)
            rowsum[blockIdx.x * 256 + threadIdx.x] = 0.f;
        return;
    }
    if (blockIdx.x >= 3072) return;
    const int zz = blockIdx.x >> 10;          // which W
    const int tb = blockIdx.x & 1023;         // tile id: 32x32 grid of 32x32 tiles
    const float* W = zz == 0 ? W0 : zz == 1 ? W1 : W2;
    _Float16*   WT = zz == 0 ? T0 : zz == 1 ? T1 : T2;
    __shared__ float tile[32][33];
    const int bxs = (tb & 31) * 32;           // source col block
    const int bys = (tb >> 5) * 32;           // source row block
    const int tx = threadIdx.x & 31;
    const int ty = threadIdx.x >> 5;          // 0..7
#pragma unroll
    for (int i = ty; i < 32; i += 8)
        tile[i][tx] = W[(size_t)(bys + i) * 1024 + bxs + tx];
    __syncthreads();
#pragma unroll
    for (int i = ty; i < 32; i += 8)
        WT[(size_t)(bxs + i) * 1024 + bys + tx] = (_Float16)tile[tx][i];
}

// ---------------------------------------------------------------------------
// B=4, Lq=Lk=2048, D=1024.
// prep (cvt+transpose+zero) -> {q,k,vT} one dispatch -> S~=exp(qk^T/32)+rowsum
// -> out = S~@v / rowsum.
// ---------------------------------------------------------------------------
extern "C" void kernel_launch(void* const* d_in, const int* in_sizes, int n_in,
                              void* d_out, int out_size, void* d_ws, size_t ws_size,
                              hipStream_t stream)
{
    const float* Xq = (const float*)d_in[0];
    const float* Xk = (const float*)d_in[1];
    const float* Xv = (const float*)d_in[2];
    const float* Wq = (const float*)d_in[3];
    const float* bq = (const float*)d_in[4];
    const float* Wk = (const float*)d_in[5];
    const float* bk = (const float*)d_in[6];
    const float* Wv = (const float*)d_in[7];
    const float* bv = (const float*)d_in[8];
    float* out = (float*)d_out;

    const size_t XN = (size_t)8192 * 1024;
    const size_t WN = (size_t)1024 * 1024;

    _Float16* ws  = (_Float16*)d_ws;
    _Float16* Xqh = ws;
    _Float16* Xkh = Xqh + XN;
    _Float16* Xvh = Xkh + XN;
    _Float16* WqT = Xvh + XN;
    _Float16* WkT = WqT + WN;
    _Float16* WvT = WkT + WN;
    _Float16* qh  = WvT + WN;
    _Float16* kh  = qh + XN;
    _Float16* vT  = kh + XN;                     // [1024 x 8192]
    _Float16* S   = vT + XN;                     // [4 x 2048 x 2048] (holds exp)
    float* rowsum = (float*)(S + (size_t)4 * 2048 * 2048);   // [8192]

    // 1. prep: convert X to f16, transpose W to f16 W^T, zero rowsum
    {
        dim3 g(8192, 4);
        prep<<<g, 256, 0, stream>>>((const float4*)Xq, Xqh,
                                    (const float4*)Xk, Xkh,
                                    (const float4*)Xv, Xvh,
                                    Wq, WqT, Wk, WkT, Wv, WvT, rowsum);
    }

    // 2. q, k, vT projections in ONE dispatch (384 blocks, 256x256 tiles)
    {
        dim3 g(8, 16, 3);
        gemm_core<0><<<g, 512, 0, stream>>>(
            Xqh, WqT, qh, bq,
            Xkh, WkT, kh, bk,
            WvT, Xvh, vT, bv,
            nullptr);
    }

    // 3. S~ = exp(q k^T / 32) f16 + atomic f32 row sums (256 blocks)
    {
        dim3 g(8, 8, 4);
        gemm_core<3><<<g, 512, 0, stream>>>(
            qh, kh, S, nullptr,
            nullptr, nullptr, nullptr, nullptr,
            nullptr, nullptr, nullptr, nullptr,
            rowsum);
    }

    // 4. out = (S~ @ v) / rowsum  (128x256 tiles, 256 blocks = full machine)
    {
        dim3 g(8, 16, 2);
        gemm_core<5><<<g, 512, 0, stream>>>(
            S, vT, out, nullptr,
            nullptr, nullptr, nullptr, nullptr,
            nullptr, nullptr, nullptr, nullptr,
            rowsum);
    }
}

// Round 5
// 305.288 us; speedup vs baseline: 1.1610x; 1.0259x over previous
//
#include <hip/hip_runtime.h>

typedef _Float16 f16x8 __attribute__((ext_vector_type(8)));
typedef _Float16 f16x4 __attribute__((ext_vector_type(4)));
typedef float f32x4 __attribute__((ext_vector_type(4)));
typedef int   v4i   __attribute__((ext_vector_type(4)));

// Async global->LDS, 16B per lane. LDS dest must be wave-uniform base; HW adds lane*16.
__device__ __forceinline__ void lds_load16(const _Float16* g, _Float16* l) {
    __builtin_amdgcn_global_load_lds(
        (const __attribute__((address_space(1))) void*)g,
        (__attribute__((address_space(3))) void*)l,
        16, 0, 0);
}

// Inline-asm LDS read, 16B at byte address a (AS(3) offset). Ordering handled
// explicitly: lgkmcnt(0)+sched_barrier(0) before MFMA use (rule #18),
// rendezvous barriers for WAR on buffer reuse.
__device__ __forceinline__ f16x8 ldsr(unsigned a) {
    v4i r;
    asm volatile("ds_read_b128 %0, %1" : "=v"(r) : "v"(a));
    return __builtin_bit_cast(f16x8, r);
}

// ---------------------------------------------------------------------------
// NT GEMM core: C[M,N] = A[M,K]*B[N,K]^T. f16 in, fp32 acc.
// 8-phase counted-vmcnt schedule (T2+T3+T4+T5) with FINE per-phase staging
// (m196's lever): tile BMxBN (256x256 or 128x256), BK=64, 512 thr = 8 waves
// (2M x 4N), wave-tile (BM/2)x64, acc[MI][4].
// Per K-tile kc (buf b=kc&1), 4 phases, each:
//   { asm ds_reads for THIS phase -> stage 2-3 gload_lds for kc+2 into the
//     regions of buf b freed by the PREVIOUS phase (WAR-safe: their reads
//     completed before that phase's trailing barrier) -> s_barrier ->
//     lgkmcnt(0) -> setprio(1) MFMA-quadrant (kh-OUTER order: 8 independent
//     MFMAs between same-acc writes) setprio(0) -> s_barrier }.
// Region free schedule (MODE0/3): A s0,s2 after ph0; B s* after ph1;
// A s1,s3 after ph2 -> staging 0/2/3/3 across phases. MODE5 (BM=128): A
// blocks split across ph0+ph2 -> staging 0/0/3/3.
// Drain: vmcnt(8) (6 for MODE5) at end of ph3 = exactly kc+2's loads newest,
// drains kc+1's (issued one K-tile earlier) -- never vmcnt(0) in steady state.
//
// LDS swizzle (both-sides, rule #21): LDS[row][slot16B] = G[row][slot ^
// (row&7)] via pre-swizzled per-lane GLOBAL source (linear gload_lds dest)
// and slot XOR on the read side. 16 lanes over 8 slots = 2-way = free.
//
// MODE 0 (BM=256): triple projection, z in {0,1,2}:
//   z=0: q  = Xqh@WqT^T + bq[n]   z=1: k = Xkh@WkT^T + bk[n]   (ldc=1024)
//   z=2: vT = WvT@Xvh^T + bv[m]   (ldc=8192)
// MODE 3 (BM=256): S~ = exp((q k^T)/32) f16 + atomic f32 row sums; z = batch
// MODE 5 (BM=128): out = (S~ @ v) * (1/rowsum[row]) f32; 256 blocks.
// ---------------------------------------------------------------------------
template <int MODE>
__global__ __launch_bounds__(512, 2)
void gemm_core(const _Float16* A0, const _Float16* B0, void* C0, const float* b0,
               const _Float16* A1, const _Float16* B1, void* C1, const float* b1,
               const _Float16* A2, const _Float16* B2, void* C2, const float* b2,
               float* rowsum)
{
    constexpr int BM  = (MODE == 5) ? 128 : 256;
    constexpr int K   = (MODE == 5) ? 2048 : 1024;
    constexpr int LDA = (MODE == 5) ? 2048 : 1024;
    constexpr int LDB = (MODE == 5) ? 8192 : 1024;
    constexpr int NT  = K / 64;
    constexpr int MI  = BM / 32;        // acc rows: 8 or 4
    constexpr int MH  = MI / 2;         // 4 or 2
    constexpr int LA  = BM / 64;        // A staging loads/thread: 4 or 2
    constexpr int LT  = LA + 4;         // loads/K-tile/thread: 8 or 6

    __shared__ __align__(16) _Float16 As[2][BM * 64];
    __shared__ __align__(16) _Float16 Bs[2][256 * 64];

    const int z_ = blockIdx.z;
    const int bx = blockIdx.x, by = blockIdx.y;
    const int t    = threadIdx.x;
    const int w    = t >> 6;
    const int lane = t & 63;
    const int ln   = lane & 15;
    const int kq   = lane >> 4;
    const int wm   = (w >> 2) * (BM / 2);
    const int wn   = (w & 3) * 64;

    const _Float16* A;
    const _Float16* B;
    size_t cbase = 0;
    int m0, n0, z = z_;

    if (MODE == 0) {
        // grid (8,16,3); XCD = bx. z0/z1: disjoint 1024-row A strips per XCD.
        A = z == 0 ? A0 : z == 1 ? A1 : A2;
        B = z == 0 ? B0 : z == 1 ? B1 : B2;
        if (z == 2) { m0 = (by & 3) * 256;             n0 = (bx * 4 + (by >> 2)) * 256; }
        else        { m0 = (bx * 4 + (by >> 2)) * 256; n0 = (by & 3) * 256; }
    } else if (MODE == 3) {
        // grid (8,8,4); XCD = bx. 2x4 super-tile per XCD.
        A = A0 + (size_t)z * 2048 * 1024;      // q slice
        B = B0 + (size_t)z * 2048 * 1024;      // k slice
        cbase = (size_t)z * 2048 * 2048;
        rowsum += z * 2048;
        m0 = ((bx & 3) * 2 + (by >> 2)) * 256;
        n0 = ((bx >> 2) * 4 + (by & 3)) * 256;
    } else {
        // grid (8,16,2); XCD = bx = (zpar<<2)|n-tile: each XCD owns one
        // 256-col vT slice x 2 z (2 MB, L2-resident); S~ streamed once.
        z = (blockIdx.z << 1) | (bx >> 2);
        A = A0 + (size_t)z * 2048 * 2048;      // S~ slice
        B = B0 + (size_t)z * 2048;             // vT col offset
        cbase = (size_t)z * 2048 * 1024;
        rowsum += z * 2048;
        m0 = by * 128;
        n0 = (bx & 3) * 256;
    }

    // ---- staging (pre-swizzled global source, linear LDS dest) ----
    // thread t: row r6 = t>>3 within each 64-row block s; global 16B-chunk
    // = (t&7) ^ (r6&7)  [LDS[r][c] = G[r][c ^ (r&7)]].
    const int r6 = t >> 3;
    const int cw = ((t & 7) ^ (r6 & 7)) * 8;
    const _Float16* gA = A + (size_t)(m0 + r6) * LDA + cw;
    const _Float16* gB = B + (size_t)(n0 + r6) * LDB + cw;

    auto stA = [&](int b, int kt, int s) {
        lds_load16(gA + (size_t)(s * 64) * LDA + kt * 64, As[b] + s * 4096 + w * 512);
    };
    auto stB = [&](int b, int kt, int s) {
        lds_load16(gB + (size_t)(s * 64) * LDB + kt * 64, Bs[b] + s * 4096 + w * 512);
    };

    // ---- read side byte addresses (AS(3) offsets) ----
    // element index: row*64 + slot, slot = (kh*4+kq) ^ (ln&7); bytes = 2x.
    const int xr  = ln & 7;
    const int sk0 = ((0 + kq) ^ xr) * 8;
    const int sk1 = ((4 + kq) ^ xr) * 8;
    const int ra  = (wm + ln) * 64;
    const int rb  = (wn + ln) * 64;

    const unsigned uA0 = (unsigned)(uintptr_t)(__attribute__((address_space(3))) _Float16*)&As[0][0];
    const unsigned uA1 = (unsigned)(uintptr_t)(__attribute__((address_space(3))) _Float16*)&As[1][0];
    const unsigned uB0 = (unsigned)(uintptr_t)(__attribute__((address_space(3))) _Float16*)&Bs[0][0];
    const unsigned uB1 = (unsigned)(uintptr_t)(__attribute__((address_space(3))) _Float16*)&Bs[1][0];
    // [buf][kh] base addrs for A-row/B-row fragment reads
    const unsigned aA[2][2] = { { uA0 + 2u * (ra + sk0), uA0 + 2u * (ra + sk1) },
                                { uA1 + 2u * (ra + sk0), uA1 + 2u * (ra + sk1) } };
    const unsigned aB[2][2] = { { uB0 + 2u * (rb + sk0), uB0 + 2u * (rb + sk1) },
                                { uB1 + 2u * (rb + sk0), uB1 + 2u * (rb + sk1) } };

    f16x8 af[MH][2], bf[4][2];
    f32x4 acc[MI][4] = {};

    // prologue: stage kt0->buf0, kt1->buf1; drain kt0 (keep kt1 in flight)
    {
#pragma unroll
        for (int s = 0; s < LA; ++s) stA(0, 0, s);
#pragma unroll
        for (int s = 0; s < 4; ++s)  stB(0, 0, s);
#pragma unroll
        for (int s = 0; s < LA; ++s) stA(1, 1, s);
#pragma unroll
        for (int s = 0; s < 4; ++s)  stB(1, 1, s);
    }
    if constexpr (MODE == 5) asm volatile("s_waitcnt vmcnt(6)" ::: "memory");
    else                     asm volatile("s_waitcnt vmcnt(8)" ::: "memory");
    __builtin_amdgcn_s_barrier();
    __builtin_amdgcn_sched_barrier(0);

#pragma unroll 2
    for (int kc = 0; kc < NT; ++kc) {
        const int  b  = kc & 1;
        const bool pf = (kc + 2 < NT);

        // ---- phase 0: reads af-lo + bf[0,1]; MFMA (i-lo, j0-1) ----
#pragma unroll
        for (int i = 0; i < MH; ++i) {
            af[i][0] = ldsr(aA[b][0] + i * 2048);
            af[i][1] = ldsr(aA[b][1] + i * 2048);
        }
#pragma unroll
        for (int j = 0; j < 2; ++j) {
            bf[j][0] = ldsr(aB[b][0] + j * 2048);
            bf[j][1] = ldsr(aB[b][1] + j * 2048);
        }
        __builtin_amdgcn_s_barrier();
        asm volatile("s_waitcnt lgkmcnt(0)" ::: "memory");
        __builtin_amdgcn_sched_barrier(0);
        __builtin_amdgcn_s_setprio(1);
#pragma unroll
        for (int kh = 0; kh < 2; ++kh)
#pragma unroll
            for (int i = 0; i < MH; ++i)
#pragma unroll
                for (int j = 0; j < 2; ++j)
                    acc[i][j] = __builtin_amdgcn_mfma_f32_16x16x32_f16(af[i][kh], bf[j][kh], acc[i][j], 0, 0, 0);
        __builtin_amdgcn_s_setprio(0);
        __builtin_amdgcn_s_barrier();
        __builtin_amdgcn_sched_barrier(0);

        // ---- phase 1: reads bf[2,3]; stage A s0,s2 (freed at ph0);
        //      MFMA (i-lo, j2-3) ----
#pragma unroll
        for (int j = 2; j < 4; ++j) {
            bf[j][0] = ldsr(aB[b][0] + j * 2048);
            bf[j][1] = ldsr(aB[b][1] + j * 2048);
        }
        if constexpr (LA == 4) {
            if (pf) { stA(b, kc + 2, 0); stA(b, kc + 2, 2); }
        }
        __builtin_amdgcn_s_barrier();
        asm volatile("s_waitcnt lgkmcnt(0)" ::: "memory");
        __builtin_amdgcn_sched_barrier(0);
        __builtin_amdgcn_s_setprio(1);
#pragma unroll
        for (int kh = 0; kh < 2; ++kh)
#pragma unroll
            for (int i = 0; i < MH; ++i)
#pragma unroll
                for (int j = 2; j < 4; ++j)
                    acc[i][j] = __builtin_amdgcn_mfma_f32_16x16x32_f16(af[i][kh], bf[j][kh], acc[i][j], 0, 0, 0);
        __builtin_amdgcn_s_setprio(0);
        __builtin_amdgcn_s_barrier();
        __builtin_amdgcn_sched_barrier(0);

        // ---- phase 2: reads af-hi (reuse regs); stage B s0-s2 (freed at
        //      ph1); MFMA (i-hi, j0-1) ----
#pragma unroll
        for (int i = 0; i < MH; ++i) {
            af[i][0] = ldsr(aA[b][0] + (i + MH) * 2048);
            af[i][1] = ldsr(aA[b][1] + (i + MH) * 2048);
        }
        if (pf) { stB(b, kc + 2, 0); stB(b, kc + 2, 1); stB(b, kc + 2, 2); }
        __builtin_amdgcn_s_barrier();
        asm volatile("s_waitcnt lgkmcnt(0)" ::: "memory");
        __builtin_amdgcn_sched_barrier(0);
        __builtin_amdgcn_s_setprio(1);
#pragma unroll
        for (int kh = 0; kh < 2; ++kh)
#pragma unroll
            for (int i = 0; i < MH; ++i)
#pragma unroll
                for (int j = 0; j < 2; ++j)
                    acc[i + MH][j] = __builtin_amdgcn_mfma_f32_16x16x32_f16(af[i][kh], bf[j][kh], acc[i + MH][j], 0, 0, 0);
        __builtin_amdgcn_s_setprio(0);
        __builtin_amdgcn_s_barrier();
        __builtin_amdgcn_sched_barrier(0);

        // ---- phase 3: stage B s3 + A-hi (A s1,s3 freed at ph2); counted
        //      drain of kc+1's loads; MFMA (i-hi, j2-3) ----
        if (pf) {
            stB(b, kc + 2, 3);
            if constexpr (LA == 4) { stA(b, kc + 2, 1); stA(b, kc + 2, 3); }
            else                   { stA(b, kc + 2, 0); stA(b, kc + 2, 1); }
            if constexpr (MODE == 5) asm volatile("s_waitcnt vmcnt(6)" ::: "memory");
            else                     asm volatile("s_waitcnt vmcnt(8)" ::: "memory");
        } else if (kc + 1 < NT) {
            asm volatile("s_waitcnt vmcnt(0)" ::: "memory");
        }
        __builtin_amdgcn_s_barrier();
        __builtin_amdgcn_sched_barrier(0);
        __builtin_amdgcn_s_setprio(1);
#pragma unroll
        for (int kh = 0; kh < 2; ++kh)
#pragma unroll
            for (int i = 0; i < MH; ++i)
#pragma unroll
                for (int j = 2; j < 4; ++j)
                    acc[i + MH][j] = __builtin_amdgcn_mfma_f32_16x16x32_f16(af[i][kh], bf[j][kh], acc[i + MH][j], 0, 0, 0);
        __builtin_amdgcn_s_setprio(0);
        __builtin_amdgcn_s_barrier();
        __builtin_amdgcn_sched_barrier(0);
    }

    // Epilogue. C/D layout: col = lane&15, row = (lane>>4)*4 + reg.
    if (MODE == 0) {
        _Float16* Cp = (_Float16*)(z == 0 ? C0 : z == 1 ? C1 : C2);
        const float* bp = z == 0 ? b0 : z == 1 ? b1 : b2;
        const int ldc = (z == 2) ? 8192 : 1024;
#pragma unroll
        for (int i = 0; i < MI; ++i) {
            const int rbase = m0 + wm + i * 16 + kq * 4;
#pragma unroll
            for (int j = 0; j < 4; ++j) {
                const int gcol = n0 + wn + j * 16 + ln;
#pragma unroll
                for (int r = 0; r < 4; ++r) {
                    float vv = acc[i][j][r] + (z == 2 ? bp[rbase + r] : bp[gcol]);
                    Cp[(size_t)(rbase + r) * ldc + gcol] = (_Float16)vv;
                }
            }
        }
    } else if (MODE == 3) {
        _Float16* Ch = (_Float16*)C0;
#pragma unroll
        for (int i = 0; i < MI; ++i) {
            const int rbase = m0 + wm + i * 16 + kq * 4;
            float rs[4] = {0.f, 0.f, 0.f, 0.f};
#pragma unroll
            for (int j = 0; j < 4; ++j) {
                const int gcol = n0 + wn + j * 16 + ln;
#pragma unroll
                for (int r = 0; r < 4; ++r) {
                    float e = __expf(acc[i][j][r] * 0.03125f);
                    Ch[cbase + (size_t)(rbase + r) * 2048 + gcol] = (_Float16)e;
                    rs[r] += e;
                }
            }
#pragma unroll
            for (int r = 0; r < 4; ++r) {
                float s = rs[r];
                s += __shfl_xor(s, 1);
                s += __shfl_xor(s, 2);
                s += __shfl_xor(s, 4);
                s += __shfl_xor(s, 8);
                if (ln == 0) atomicAdd(&rowsum[rbase + r], s);
            }
        }
    } else {
        float* Cf = (float*)C0;
#pragma unroll
        for (int i = 0; i < MI; ++i) {
            const int rbase = m0 + wm + i * 16 + kq * 4;
            float inv[4];
#pragma unroll
            for (int r = 0; r < 4; ++r) inv[r] = 1.f / rowsum[rbase + r];
#pragma unroll
            for (int j = 0; j < 4; ++j) {
                const int gcol = n0 + wn + j * 16 + ln;
#pragma unroll
                for (int r = 0; r < 4; ++r)
                    Cf[cbase + (size_t)(rbase + r) * 1024 + gcol] = acc[i][j][r] * inv[r];
            }
        }
    }
}

// ---------------------------------------------------------------------------
// Prep kernel, ONE launch. grid (8192, 4), 256 threads:
//   y in {0,1,2}: f32->f16 convert of X_y (float4/thread); y==0,x<32 zeros rowsum.
//   y==3, x<3072: 32x32 transpose tile of W_{x/1024} -> f16 W^T.
// ---------------------------------------------------------------------------
__global__ __launch_bounds__(256)
void prep(const float4* __restrict__ x0, _Float16* __restrict__ y0,
          const float4* __restrict__ x1, _Float16* __restrict__ y1,
          const float4* __restrict__ x2, _Float16* __restrict__ y2,
          const float* __restrict__ W0, _Float16* __restrict__ T0,
          const float* __restrict__ W1, _Float16* __restrict__ T1,
          const float* __restrict__ W2, _Float16* __restrict__ T2,
          float* __restrict__ rowsum)
{
    if (blockIdx.y < 3) {
        const size_t i = (size_t)blockIdx.x * 256 + threadIdx.x;
        const float4* x = blockIdx.y == 0 ? x0 : blockIdx.y == 1 ? x1 : x2;
        _Float16*    yy = blockIdx.y == 0 ? y0 : blockIdx.y == 1 ? y1 : y2;
        float4 f = x[i];
        f16x4 o = { (_Float16)f.x, (_Float16)f.y, (_Float16)f.z, (_Float16)f.w };
        *(f16x4*)(yy + i * 4) = o;
        if (blockIdx.y == 0 && blockIdx.x < 32)
            rowsum[blockIdx.x * 256 + threadIdx.x] = 0.f;
        return;
    }
    if (blockIdx.x >= 3072) return;
    const int zz = blockIdx.x >> 10;          // which W
    const int tb = blockIdx.x & 1023;         // tile id: 32x32 grid of 32x32 tiles
    const float* W = zz == 0 ? W0 : zz == 1 ? W1 : W2;
    _Float16*   WT = zz == 0 ? T0 : zz == 1 ? T1 : T2;
    __shared__ float tile[32][33];
    const int bxs = (tb & 31) * 32;           // source col block
    const int bys = (tb >> 5) * 32;           // source row block
    const int tx = threadIdx.x & 31;
    const int ty = threadIdx.x >> 5;          // 0..7
#pragma unroll
    for (int i = ty; i < 32; i += 8)
        tile[i][tx] = W[(size_t)(bys + i) * 1024 + bxs + tx];
    __syncthreads();
#pragma unroll
    for (int i = ty; i < 32; i += 8)
        WT[(size_t)(bxs + i) * 1024 + bys + tx] = (_Float16)tile[tx][i];
}

// ---------------------------------------------------------------------------
// B=4, Lq=Lk=2048, D=1024.
// prep (cvt+transpose+zero) -> {q,k,vT} one dispatch -> S~=exp(qk^T/32)+rowsum
// -> out = S~@v / rowsum.
// ---------------------------------------------------------------------------
extern "C" void kernel_launch(void* const* d_in, const int* in_sizes, int n_in,
                              void* d_out, int out_size, void* d_ws, size_t ws_size,
                              hipStream_t stream)
{
    const float* Xq = (const float*)d_in[0];
    const float* Xk = (const float*)d_in[1];
    const float* Xv = (const float*)d_in[2];
    const float* Wq = (const float*)d_in[3];
    const float* bq = (const float*)d_in[4];
    const float* Wk = (const float*)d_in[5];
    const float* bk = (const float*)d_in[6];
    const float* Wv = (const float*)d_in[7];
    const float* bv = (const float*)d_in[8];
    float* out = (float*)d_out;

    const size_t XN = (size_t)8192 * 1024;
    const size_t WN = (size_t)1024 * 1024;

    _Float16* ws  = (_Float16*)d_ws;
    _Float16* Xqh = ws;
    _Float16* Xkh = Xqh + XN;
    _Float16* Xvh = Xkh + XN;
    _Float16* WqT = Xvh + XN;
    _Float16* WkT = WqT + WN;
    _Float16* WvT = WkT + WN;
    _Float16* qh  = WvT + WN;
    _Float16* kh  = qh + XN;
    _Float16* vT  = kh + XN;                     // [1024 x 8192]
    _Float16* S   = vT + XN;                     // [4 x 2048 x 2048] (holds exp)
    float* rowsum = (float*)(S + (size_t)4 * 2048 * 2048);   // [8192]

    // 1. prep: convert X to f16, transpose W to f16 W^T, zero rowsum
    {
        dim3 g(8192, 4);
        prep<<<g, 256, 0, stream>>>((const float4*)Xq, Xqh,
                                    (const float4*)Xk, Xkh,
                                    (const float4*)Xv, Xvh,
                                    Wq, WqT, Wk, WkT, Wv, WvT, rowsum);
    }

    // 2. q, k, vT projections in ONE dispatch (384 blocks, 256x256 tiles)
    {
        dim3 g(8, 16, 3);
        gemm_core<0><<<g, 512, 0, stream>>>(
            Xqh, WqT, qh, bq,
            Xkh, WkT, kh, bk,
            WvT, Xvh, vT, bv,
            nullptr);
    }

    // 3. S~ = exp(q k^T / 32) f16 + atomic f32 row sums (256 blocks)
    {
        dim3 g(8, 8, 4);
        gemm_core<3><<<g, 512, 0, stream>>>(
            qh, kh, S, nullptr,
            nullptr, nullptr, nullptr, nullptr,
            nullptr, nullptr, nullptr, nullptr,
            rowsum);
    }

    // 4. out = (S~ @ v) / rowsum  (128x256 tiles, 256 blocks = full machine)
    {
        dim3 g(8, 16, 2);
        gemm_core<5><<<g, 512, 0, stream>>>(
            S, vT, out, nullptr,
            nullptr, nullptr, nullptr, nullptr,
            nullptr, nullptr, nullptr, nullptr,
            rowsum);
    }
}